// Round 1
// baseline (937.869 us; speedup 1.0000x reference)
//
#include <hip/hip_runtime.h>
#include <hip/hip_bf16.h>

#define S_DIM 1024
#define B_DIM 4
#define D_DIM 1024
#define H_DIM 16
#define DH    64
#define T_DIM (S_DIM * B_DIM)   // 4096
#define QKV_N (3 * D_DIM)       // 3072

using bf16 = __hip_bfloat16;
typedef __attribute__((ext_vector_type(4))) float fx4;
typedef __attribute__((ext_vector_type(8))) short bx8;

__device__ __forceinline__ unsigned short f2bf(float f) {
  union { float f; unsigned int u; } cv; cv.f = f;
  unsigned int u = cv.u;
  unsigned int r = (u + 0x7FFFu + ((u >> 16) & 1u)) >> 16;  // RNE
  return (unsigned short)r;
}

__device__ __forceinline__ void g2l16(const void* g, void* l) {
  __builtin_amdgcn_global_load_lds(
      (const __attribute__((address_space(1))) unsigned int*)g,
      (__attribute__((address_space(3))) unsigned int*)l, 16, 0, 0);
}

// ---------------- cast fp32 -> bf16 (vectorized) ----------------
__global__ __launch_bounds__(256) void cast_f32_bf16(
    const float* __restrict__ src, bf16* __restrict__ dst, int n4) {
  const int i = blockIdx.x * 256 + threadIdx.x;
  if (i >= n4) return;
  const fx4 v = ((const fx4*)src)[i];
  ushort4 u;
  u.x = f2bf(v[0]); u.y = f2bf(v[1]); u.z = f2bf(v[2]); u.w = f2bf(v[3]);
  ((ushort4*)dst)[i] = u;
}

// ---------------- LN (row of 1024) -> bf16 ----------------
__global__ __launch_bounds__(256) void ln_bf16_kernel(
    const float* __restrict__ x, const float* __restrict__ w,
    const float* __restrict__ bb, bf16* __restrict__ out) {
  const int t = blockIdx.x, tid = threadIdx.x;
  const fx4 v = ((const fx4*)(x + (size_t)t * D_DIM))[tid];
  float s  = v[0] + v[1] + v[2] + v[3];
  float ss = v[0]*v[0] + v[1]*v[1] + v[2]*v[2] + v[3]*v[3];
#pragma unroll
  for (int off = 32; off >= 1; off >>= 1) {
    s  += __shfl_xor(s, off);
    ss += __shfl_xor(ss, off);
  }
  __shared__ float red[8];
  const int wid = tid >> 6, lane = tid & 63;
  if (lane == 0) { red[wid] = s; red[4 + wid] = ss; }
  __syncthreads();
  s  = red[0] + red[1] + red[2] + red[3];
  ss = red[4] + red[5] + red[6] + red[7];
  const float mu = s * (1.f / D_DIM);
  const float rstd = rsqrtf(ss * (1.f / D_DIM) - mu * mu + 1e-5f);
  const fx4 wv = ((const fx4*)w)[tid];
  const fx4 bv = ((const fx4*)bb)[tid];
  ushort4 u;
  u.x = f2bf((v[0] - mu) * rstd * wv[0] + bv[0]);
  u.y = f2bf((v[1] - mu) * rstd * wv[1] + bv[1]);
  u.z = f2bf((v[2] - mu) * rstd * wv[2] + bv[2]);
  u.w = f2bf((v[3] - mu) * rstd * wv[3] + bv[3]);
  ((ushort4*)(out + (size_t)t * D_DIM))[tid] = u;
}

// ---------------- bf16 MFMA GEMM: C[M,N] = A[M,K] @ B[N,K]^T (+bias[,+resid]) ----------------
// m97-style: 128x128 tile, 4 waves (2x2), 16x16x32 frags, global_load_lds width 16.
template <int EPI>  // 0: C = acc + bias (fp32 out). 1: C = acc + bias + resid.
__global__ __launch_bounds__(256, 2) void gemm_bt(
    const bf16* __restrict__ A, const bf16* __restrict__ B,
    const float* __restrict__ bias, const float* __restrict__ resid,
    float* __restrict__ C, int M, int N, int K) {
  (void)M;
  __shared__ bf16 sA[128 * 32];
  __shared__ bf16 sB[128 * 32];
  const int tid  = threadIdx.x;
  const int brow = blockIdx.y * 128;
  const int bcol = blockIdx.x * 128;
  const int wid  = tid >> 6;
  const int lane = tid & 63;
  const int wr   = wid >> 1;
  const int wc   = wid & 1;
  const int fr   = lane & 15;   // A-row / B-col within fragment
  const int fk   = lane >> 4;   // k-group: k = fk*8 + j

  fx4 acc[4][4];
#pragma unroll
  for (int i = 0; i < 4; ++i)
#pragma unroll
    for (int j = 0; j < 4; ++j) acc[i][j] = 0.f;

  const int arow = tid >> 2;        // 0..63
  const int acol = (tid & 3) * 8;   // bf16 col within 32-wide K slab

  for (int kt = 0; kt < K; kt += 32) {
    __syncthreads();  // WAR on LDS
#pragma unroll
    for (int is = 0; is < 2; ++is) {
      const int row = is * 64 + arow;
      const int off = row * 64 + acol * 2;  // linear LDS byte offset
      g2l16(A + (size_t)(brow + row) * K + kt + acol, (char*)sA + off);
      g2l16(B + (size_t)(bcol + row) * K + kt + acol, (char*)sB + off);
    }
    __syncthreads();  // drains vmcnt for global_load_lds

    bx8 af[4], bfr[4];
#pragma unroll
    for (int mm = 0; mm < 4; ++mm)
      af[mm] = *(const bx8*)(sA + (wr * 64 + mm * 16 + fr) * 32 + fk * 8);
#pragma unroll
    for (int nn = 0; nn < 4; ++nn)
      bfr[nn] = *(const bx8*)(sB + (wc * 64 + nn * 16 + fr) * 32 + fk * 8);
#pragma unroll
    for (int mm = 0; mm < 4; ++mm)
#pragma unroll
      for (int nn = 0; nn < 4; ++nn)
        acc[mm][nn] = __builtin_amdgcn_mfma_f32_16x16x32_bf16(
            af[mm], bfr[nn], acc[mm][nn], 0, 0, 0);
  }

  // C/D layout (m89-verified): col = lane&15, row = (lane>>4)*4 + reg
  const int row0 = brow + wr * 64 + fk * 4;
  const int col0 = bcol + wc * 64 + fr;
#pragma unroll
  for (int mm = 0; mm < 4; ++mm) {
#pragma unroll
    for (int nn = 0; nn < 4; ++nn) {
      const int col = col0 + nn * 16;
      const float bv = bias[col];
#pragma unroll
      for (int rr = 0; rr < 4; ++rr) {
        const int row = row0 + mm * 16 + rr;
        float v = acc[mm][nn][rr] + bv;
        if (EPI == 1) v += resid[(size_t)row * N + col];
        C[(size_t)row * N + col] = v;
      }
    }
  }
}

// ---------------- causal attention, fp32 vector math ----------------
// qkv fp32 [T][3072] rows t = s*B+b. 2048 chunks of 32 q-rows (bh-major:
// c = bh*32 + qc). One wave per chunk; lane = 32*half + r owns q-row q0+r,
// d-half [32*half, 32*half+32). Slot pairing balances causal load.
__global__ __launch_bounds__(256) void attn_kernel(
    const float* __restrict__ qkv, bf16* __restrict__ o) {
  const int slot = blockIdx.x * 4 + (threadIdx.x >> 6);
  const int lane = threadIdx.x & 63;
  const int c    = (slot < 1024) ? slot : (3071 - slot);
  const int bh   = c >> 5;
  const int qc   = c & 31;
  const int b    = bh >> 4;   // bh = b*H + h
  const int h    = bh & 15;
  const int half = lane >> 5;
  const int r    = lane & 31;
  const int q0   = qc * 32;
  const int qrow = q0 + r;

  const float* qp = qkv + ((size_t)qrow * B_DIM + b) * QKV_N + h * DH + half * 32;
  fx4 q4[8], o4[8];
#pragma unroll
  for (int j = 0; j < 8; ++j) {
    q4[j] = ((const fx4*)qp)[j] * 0.125f;  // DH^-0.5
    o4[j] = 0.f;
  }
  float m = -INFINITY, sum = 0.f;
  const float* kb = qkv + (size_t)b * QKV_N + D_DIM + h * DH + half * 32;
  const float* vb = kb + D_DIM;
  const int smax = q0 + 31;

  for (int s2 = 0; s2 <= smax; ++s2) {
    const fx4* kr = (const fx4*)(kb + (size_t)s2 * (B_DIM * QKV_N));
    float sc = 0.f;
#pragma unroll
    for (int j = 0; j < 8; ++j) {
      const fx4 kv = kr[j];
      sc += q4[j][0]*kv[0] + q4[j][1]*kv[1] + q4[j][2]*kv[2] + q4[j][3]*kv[3];
    }
    sc += __shfl_xor(sc, 32);  // combine d-halves
    const bool ok = (s2 <= qrow);
    if (ok && sc > m) {        // rare lazy rescale
      const float rs = __expf(m - sc);
      m = sc; sum *= rs;
#pragma unroll
      for (int j = 0; j < 8; ++j) o4[j] *= rs;
    }
    const float p = ok ? __expf(sc - m) : 0.f;
    sum += p;
    const fx4* vr = (const fx4*)(vb + (size_t)s2 * (B_DIM * QKV_N));
#pragma unroll
    for (int j = 0; j < 8; ++j) o4[j] += p * vr[j];
  }

  const float inv = 1.f / sum;
  bf16* op = o + ((size_t)qrow * B_DIM + b) * D_DIM + h * DH + half * 32;
#pragma unroll
  for (int j = 0; j < 8; ++j) {
    const fx4 v = o4[j] * inv;
    ushort4 u;
    u.x = f2bf(v[0]); u.y = f2bf(v[1]); u.z = f2bf(v[2]); u.w = f2bf(v[3]);
    ((ushort4*)op)[j] = u;
  }
}

// ---------------- LN2 + router + gate + final multiply ----------------
__global__ __launch_bounds__(256) void final_kernel(
    const float* __restrict__ xn, const float* __restrict__ w,
    const float* __restrict__ bb, const float* __restrict__ gw,
    float* __restrict__ out, float* __restrict__ rlog) {
  const int t = blockIdx.x, tid = threadIdx.x;
  const fx4 v = ((const fx4*)(xn + (size_t)t * D_DIM))[tid];
  float s  = v[0] + v[1] + v[2] + v[3];
  float ss = v[0]*v[0] + v[1]*v[1] + v[2]*v[2] + v[3]*v[3];
#pragma unroll
  for (int off = 32; off >= 1; off >>= 1) {
    s  += __shfl_xor(s, off);
    ss += __shfl_xor(ss, off);
  }
  __shared__ float red[8];
  __shared__ float red2[12];
  const int wid = tid >> 6, lane = tid & 63;
  if (lane == 0) { red[wid] = s; red[4 + wid] = ss; }
  __syncthreads();
  s  = red[0] + red[1] + red[2] + red[3];
  ss = red[4] + red[5] + red[6] + red[7];
  const float mu = s * (1.f / D_DIM);
  const float rstd = rsqrtf(ss * (1.f / D_DIM) - mu * mu + 1e-5f);
  const fx4 wv = ((const fx4*)w)[tid];
  const fx4 bv = ((const fx4*)bb)[tid];
  fx4 hv;
#pragma unroll
  for (int cc = 0; cc < 4; ++cc) hv[cc] = (v[cc] - mu) * rstd * wv[cc] + bv[cc];

  const fx4 w0 = ((const fx4*)(gw           ))[tid];
  const fx4 w1 = ((const fx4*)(gw +     D_DIM))[tid];
  const fx4 w2 = ((const fx4*)(gw + 2 * D_DIM))[tid];
  float g0 = hv[0]*w0[0] + hv[1]*w0[1] + hv[2]*w0[2] + hv[3]*w0[3];
  float g1 = hv[0]*w1[0] + hv[1]*w1[1] + hv[2]*w1[2] + hv[3]*w1[3];
  float g2 = hv[0]*w2[0] + hv[1]*w2[1] + hv[2]*w2[2] + hv[3]*w2[3];
#pragma unroll
  for (int off = 32; off >= 1; off >>= 1) {
    g0 += __shfl_xor(g0, off);
    g1 += __shfl_xor(g1, off);
    g2 += __shfl_xor(g2, off);
  }
  if (lane == 0) { red2[wid] = g0; red2[4 + wid] = g1; red2[8 + wid] = g2; }
  __syncthreads();
  g0 = red2[0] + red2[1] + red2[2]  + red2[3];
  g1 = red2[4] + red2[5] + red2[6]  + red2[7];
  g2 = red2[8] + red2[9] + red2[10] + red2[11];

  // gate = pmax/(pmax+p2nd) of softmax over 3 = 1/(1+exp(l_mid - l_max))
  const float lmax = fmaxf(g0, fmaxf(g1, g2));
  const float lmin = fminf(g0, fminf(g1, g2));
  const float lmid = (g0 + g1 + g2) - lmax - lmin;
  const float gate = 1.f / (1.f + __expf(lmid - lmax));

  ((fx4*)(out + (size_t)t * D_DIM))[tid] = v * gate;
  if (tid == 0) {
    rlog[(size_t)t * 3 + 0] = g0;
    rlog[(size_t)t * 3 + 1] = g1;
    rlog[(size_t)t * 3 + 2] = g2;
  }
}

extern "C" void kernel_launch(void* const* d_in, const int* in_sizes, int n_in,
                              void* d_out, int out_size, void* d_ws, size_t ws_size,
                              hipStream_t stream) {
  (void)in_sizes; (void)n_in; (void)out_size; (void)ws_size;
  const float* x    = (const float*)d_in[0];
  const float* ln1w = (const float*)d_in[1];
  const float* ln1b = (const float*)d_in[2];
  const float* ln2w = (const float*)d_in[3];
  const float* ln2b = (const float*)d_in[4];
  const float* win  = (const float*)d_in[5];
  const float* bin  = (const float*)d_in[6];
  const float* wout = (const float*)d_in[7];
  const float* bout = (const float*)d_in[8];
  const float* gw   = (const float*)d_in[9];
  // fc_w / fc_b / proj_w / proj_b (d_in[10..13]) are dead code in the reference.

  char* ws = (char*)d_ws;
  bf16*  w_in_b  = (bf16*)(ws);               // 6,291,456 B
  bf16*  w_out_b = (bf16*)(ws + 6291456);     // 2,097,152 B
  bf16*  h_b     = (bf16*)(ws + 8388608);     // 8,388,608 B (LN1 out)
  bf16*  o_b     = h_b;                       // alias: h dead after GEMM1
  float* qkv     = (float*)(ws + 16777216);   // 50,331,648 B
  float* xnew    = qkv;                       // alias: qkv dead after attention
  // total ws use: 64 MiB

  float* out  = (float*)d_out;
  float* rlog = out + (size_t)T_DIM * D_DIM;

  cast_f32_bf16<<<(3145728 / 4) / 256, 256, 0, stream>>>(win,  w_in_b,  3145728 / 4);
  cast_f32_bf16<<<(1048576 / 4) / 256, 256, 0, stream>>>(wout, w_out_b, 1048576 / 4);
  ln_bf16_kernel<<<T_DIM, 256, 0, stream>>>(x, ln1w, ln1b, h_b);
  gemm_bt<0><<<dim3(QKV_N / 128, T_DIM / 128), 256, 0, stream>>>(
      h_b, w_in_b, bin, nullptr, qkv, T_DIM, QKV_N, D_DIM);
  attn_kernel<<<512, 256, 0, stream>>>(qkv, o_b);
  gemm_bt<1><<<dim3(D_DIM / 128, T_DIM / 128), 256, 0, stream>>>(
      o_b, w_out_b, bout, x, xnew, T_DIM, D_DIM, D_DIM);
  final_kernel<<<T_DIM, 256, 0, stream>>>(xnew, ln2w, ln2b, gw, out, rlog);
}

// Round 2
// 139.165 us; speedup vs baseline: 6.7393x; 6.7393x over previous
//
#include <hip/hip_runtime.h>
#include <hip/hip_bf16.h>

#define S_DIM 1024
#define B_DIM 4
#define D_DIM 1024
#define H_DIM 16
#define DH    64
#define T_DIM (S_DIM * B_DIM)   // 4096
#define QKV_N (3 * D_DIM)       // 3072

using bf16 = __hip_bfloat16;
typedef __attribute__((ext_vector_type(4))) float fx4;
typedef __attribute__((ext_vector_type(8))) short bx8;

__device__ __forceinline__ unsigned short f2bf(float f) {
  union { float f; unsigned int u; } cv; cv.f = f;
  unsigned int u = cv.u;
  unsigned int r = (u + 0x7FFFu + ((u >> 16) & 1u)) >> 16;  // RNE
  return (unsigned short)r;
}

__device__ __forceinline__ void g2l16(const void* g, void* l) {
  __builtin_amdgcn_global_load_lds(
      (const __attribute__((address_space(1))) unsigned int*)g,
      (__attribute__((address_space(3))) unsigned int*)l, 16, 0, 0);
}

// ---------------- cast fp32 -> bf16 (vectorized) ----------------
__global__ __launch_bounds__(256) void cast_f32_bf16(
    const float* __restrict__ src, bf16* __restrict__ dst, int n4) {
  const int i = blockIdx.x * 256 + threadIdx.x;
  if (i >= n4) return;
  const fx4 v = ((const fx4*)src)[i];
  ushort4 u;
  u.x = f2bf(v[0]); u.y = f2bf(v[1]); u.z = f2bf(v[2]); u.w = f2bf(v[3]);
  ((ushort4*)dst)[i] = u;
}

// ---------------- LN (row of 1024) -> bf16 ----------------
__global__ __launch_bounds__(256) void ln_bf16_kernel(
    const float* __restrict__ x, const float* __restrict__ w,
    const float* __restrict__ bb, bf16* __restrict__ out) {
  const int t = blockIdx.x, tid = threadIdx.x;
  const fx4 v = ((const fx4*)(x + (size_t)t * D_DIM))[tid];
  float s  = v[0] + v[1] + v[2] + v[3];
  float ss = v[0]*v[0] + v[1]*v[1] + v[2]*v[2] + v[3]*v[3];
#pragma unroll
  for (int off = 32; off >= 1; off >>= 1) {
    s  += __shfl_xor(s, off);
    ss += __shfl_xor(ss, off);
  }
  __shared__ float red[8];
  const int wid = tid >> 6, lane = tid & 63;
  if (lane == 0) { red[wid] = s; red[4 + wid] = ss; }
  __syncthreads();
  s  = red[0] + red[1] + red[2] + red[3];
  ss = red[4] + red[5] + red[6] + red[7];
  const float mu = s * (1.f / D_DIM);
  const float rstd = rsqrtf(ss * (1.f / D_DIM) - mu * mu + 1e-5f);
  const fx4 wv = ((const fx4*)w)[tid];
  const fx4 bv = ((const fx4*)bb)[tid];
  ushort4 u;
  u.x = f2bf((v[0] - mu) * rstd * wv[0] + bv[0]);
  u.y = f2bf((v[1] - mu) * rstd * wv[1] + bv[1]);
  u.z = f2bf((v[2] - mu) * rstd * wv[2] + bv[2]);
  u.w = f2bf((v[3] - mu) * rstd * wv[3] + bv[3]);
  ((ushort4*)(out + (size_t)t * D_DIM))[tid] = u;
}

// ---------------- bf16 MFMA GEMM: C[M,N] = A[M,K] @ B[N,K]^T ----------------
// m97-style: 128x128 tile, 4 waves (2x2), 16x16x32 frags, global_load_lds w=16.
// EPI 1: C(fp32) = acc + bias + resid.
// EPI 2: qkv split-write: bf16 to q/k/v [bh][s][64], q scaled by 0.125.
template <int EPI>
__global__ __launch_bounds__(256, 2) void gemm_bt(
    const bf16* __restrict__ A, const bf16* __restrict__ B,
    const float* __restrict__ bias, const float* __restrict__ resid,
    float* __restrict__ C, ushort* __restrict__ qkvb, int N, int K) {
  __shared__ bf16 sA[128 * 32];
  __shared__ bf16 sB[128 * 32];
  const int tid  = threadIdx.x;
  const int brow = blockIdx.y * 128;
  const int bcol = blockIdx.x * 128;
  const int wid  = tid >> 6;
  const int lane = tid & 63;
  const int wr   = wid >> 1;
  const int wc   = wid & 1;
  const int fr   = lane & 15;
  const int fk   = lane >> 4;

  fx4 acc[4][4];
#pragma unroll
  for (int i = 0; i < 4; ++i)
#pragma unroll
    for (int j = 0; j < 4; ++j) acc[i][j] = 0.f;

  const int arow = tid >> 2;
  const int acol = (tid & 3) * 8;

  for (int kt = 0; kt < K; kt += 32) {
    __syncthreads();
#pragma unroll
    for (int is = 0; is < 2; ++is) {
      const int row = is * 64 + arow;
      const int off = row * 64 + acol * 2;
      g2l16(A + (size_t)(brow + row) * K + kt + acol, (char*)sA + off);
      g2l16(B + (size_t)(bcol + row) * K + kt + acol, (char*)sB + off);
    }
    __syncthreads();

    bx8 af[4], bfr[4];
#pragma unroll
    for (int mm = 0; mm < 4; ++mm)
      af[mm] = *(const bx8*)(sA + (wr * 64 + mm * 16 + fr) * 32 + fk * 8);
#pragma unroll
    for (int nn = 0; nn < 4; ++nn)
      bfr[nn] = *(const bx8*)(sB + (wc * 64 + nn * 16 + fr) * 32 + fk * 8);
#pragma unroll
    for (int mm = 0; mm < 4; ++mm)
#pragma unroll
      for (int nn = 0; nn < 4; ++nn)
        acc[mm][nn] = __builtin_amdgcn_mfma_f32_16x16x32_bf16(
            af[mm], bfr[nn], acc[mm][nn], 0, 0, 0);
  }

  // C/D layout: col = lane&15, row = (lane>>4)*4 + reg
  const int row0 = brow + wr * 64 + fk * 4;
  const int col0 = bcol + wc * 64 + fr;
#pragma unroll
  for (int mm = 0; mm < 4; ++mm) {
#pragma unroll
    for (int nn = 0; nn < 4; ++nn) {
      const int col = col0 + nn * 16;
      const float bv = bias[col];
      if (EPI == 1) {
#pragma unroll
        for (int rr = 0; rr < 4; ++rr) {
          const int row = row0 + mm * 16 + rr;
          C[(size_t)row * N + col] = acc[mm][nn][rr] + bv + resid[(size_t)row * N + col];
        }
      } else {  // EPI == 2
        const int which = col >> 10;          // 0=q 1=k 2=v
        const int rem   = col & 1023;
        const int hh    = rem >> 6;
        const int dh    = rem & 63;
        const float scale = (which == 0) ? 0.125f : 1.0f;
#pragma unroll
        for (int rr = 0; rr < 4; ++rr) {
          const int row = row0 + mm * 16 + rr;  // t = s*B + b
          const int ss2 = row >> 2, bb2 = row & 3;
          const float v = (acc[mm][nn][rr] + bv) * scale;
          qkvb[(size_t)which * 4194304 +
               ((size_t)(bb2 * 16 + hh)) * 65536 + (size_t)ss2 * 64 + dh] = f2bf(v);
        }
      }
    }
  }
}

// ---------------- MFMA flash attention ----------------
// Block = (bh, q-tile of 64). 4 waves x 16 q-rows. 64-key blocks, causal.
// K in LDS via global_load_lds with pre-swizzled source; V^T reg-transposed
// into swizzled LDS; P through per-wave swizzled LDS tile. All tiles use
// byte ^= ((row&7)<<4) swizzle to kill the stride-128B bank conflict.
__global__ __launch_bounds__(256, 4) void attn_mfma(
    const ushort* __restrict__ qb, const ushort* __restrict__ kb,
    const ushort* __restrict__ vb, ushort* __restrict__ ob) {
  __shared__ __align__(16) char sK[8192];
  __shared__ __align__(16) char sVT[8192];
  __shared__ __align__(16) char sP[8192];
  const int tid  = threadIdx.x;
  const int wid  = tid >> 6;
  const int lane = tid & 63;
  // pair q-tiles t and 15-t so consecutive blocks have equal causal work
  const int g  = blockIdx.x;
  const int u  = g >> 1;
  const int pr = u & 7;
  const int qt = (g & 1) ? (15 - pr) : pr;
  const int bh = u >> 3;
  const int b  = bh >> 4, h = bh & 15;
  const int q0 = qt * 64;
  const int fr = lane & 15;
  const int fk = lane >> 4;
  const size_t bhoff = (size_t)bh * 65536;

  // Q A-fragments (rows q0 + wid*16 + fr), pre-scaled by DH^-0.5 upstream
  const int qrow = q0 + wid * 16 + fr;
  const bx8 qf0 = *(const bx8*)(qb + bhoff + (size_t)qrow * 64 + fk * 8);
  const bx8 qf1 = *(const bx8*)(qb + bhoff + (size_t)qrow * 64 + 32 + fk * 8);

  fx4 o4[4];
  float m[4], l[4];
#pragma unroll
  for (int dt = 0; dt < 4; ++dt) o4[dt] = 0.f;
#pragma unroll
  for (int rr = 0; rr < 4; ++rr) { m[rr] = -INFINITY; l[rr] = 0.f; }

  char* const sPw = sP + wid * 2048;

  for (int kbk = 0; kbk <= qt; ++kbk) {
    const int k0 = kbk * 64;
    __syncthreads();  // WAR on sK/sVT
    // --- stage K [64 keys][64 dh] bf16, source pre-swizzled, LDS linear ---
#pragma unroll
    for (int is = 0; is < 2; ++is) {
      const int L    = is * 4096 + tid * 16;
      const int row  = L >> 7;
      const int colb = (L & 127) ^ ((row & 7) << 4);
      g2l16(kb + bhoff + (size_t)(k0 + row) * 64 + (colb >> 1), sK + L);
    }
    // --- stage V^T [64 dh][64 keys] via register transpose, swizzled ---
    {
      const ushort* vp = vb + bhoff + (size_t)(k0 + lane) * 64 + wid * 16;
      const bx8 va  = *(const bx8*)vp;
      const bx8 vb2 = *(const bx8*)(vp + 8);
#pragma unroll
      for (int i = 0; i < 8; ++i) {
        const int dh0 = wid * 16 + i;
        *(ushort*)(sVT + ((dh0 * 128 + lane * 2) ^ ((i & 7) << 4))) = (ushort)va[i];
        const int dh1 = dh0 + 8;
        *(ushort*)(sVT + ((dh1 * 128 + lane * 2) ^ ((i & 7) << 4))) = (ushort)vb2[i];
      }
    }
    __syncthreads();

    // --- S = Q K^T : 4 key-tiles of 16, dh = 2 chunks of 32 ---
    fx4 s4[4];
#pragma unroll
    for (int kt = 0; kt < 4; ++kt) {
      const int krow = kt * 16 + fr;
      const int sw   = (krow & 7) << 4;
      const bx8 b0 = *(const bx8*)(sK + krow * 128 + ((fk * 16) ^ sw));
      const bx8 b1 = *(const bx8*)(sK + krow * 128 + ((64 + fk * 16) ^ sw));
      fx4 z = {0.f, 0.f, 0.f, 0.f};
      z = __builtin_amdgcn_mfma_f32_16x16x32_bf16(qf0, b0, z, 0, 0, 0);
      s4[kt] = __builtin_amdgcn_mfma_f32_16x16x32_bf16(qf1, b1, z, 0, 0, 0);
    }

    if (kbk == qt) {  // diagonal block: causal mask
#pragma unroll
      for (int kt = 0; kt < 4; ++kt) {
        const int key = k0 + kt * 16 + fr;
#pragma unroll
        for (int rr = 0; rr < 4; ++rr) {
          const int qq = q0 + wid * 16 + fk * 4 + rr;
          if (key > qq) s4[kt][rr] = -INFINITY;
        }
      }
    }

    // --- online softmax: row = (lane>>4)*4+rr, cols across 16-lane group ---
    float pm[4];
#pragma unroll
    for (int rr = 0; rr < 4; ++rr)
      pm[rr] = fmaxf(fmaxf(s4[0][rr], s4[1][rr]), fmaxf(s4[2][rr], s4[3][rr]));
#pragma unroll
    for (int off = 1; off <= 8; off <<= 1)
#pragma unroll
      for (int rr = 0; rr < 4; ++rr)
        pm[rr] = fmaxf(pm[rr], __shfl_xor(pm[rr], off));

#pragma unroll
    for (int rr = 0; rr < 4; ++rr) {
      const float mn = fmaxf(m[rr], pm[rr]);
      const float f  = __expf(m[rr] - mn);  // first iter: exp(-inf)=0
      m[rr] = mn;
      l[rr] *= f;
#pragma unroll
      for (int dt = 0; dt < 4; ++dt) o4[dt][rr] *= f;
    }

#pragma unroll
    for (int kt = 0; kt < 4; ++kt) {
#pragma unroll
      for (int rr = 0; rr < 4; ++rr) {
        const float pv = __expf(s4[kt][rr] - m[rr]);
        l[rr] += pv;  // lane-partial row sum; cross-lane reduce deferred
        const int qr = fk * 4 + rr;
        *(ushort*)(sPw + ((qr * 128 + (kt * 16 + fr) * 2) ^ ((qr & 7) << 4))) = f2bf(pv);
      }
    }

    // --- O += P V : A = P[16q x 64k] from LDS, B = V^T[dh][k] ---
#pragma unroll
    for (int c = 0; c < 2; ++c) {
      const bx8 pa = *(const bx8*)(sPw + fr * 128 + ((c * 64 + fk * 16) ^ ((fr & 7) << 4)));
#pragma unroll
      for (int dt = 0; dt < 4; ++dt) {
        const int vrow = dt * 16 + fr;
        const bx8 vf = *(const bx8*)(sVT + vrow * 128 + ((c * 64 + fk * 16) ^ ((vrow & 7) << 4)));
        o4[dt] = __builtin_amdgcn_mfma_f32_16x16x32_bf16(pa, vf, o4[dt], 0, 0, 0);
      }
    }
  }

  // finish row sums (lane partials -> full row), normalize, store
#pragma unroll
  for (int off = 1; off <= 8; off <<= 1)
#pragma unroll
    for (int rr = 0; rr < 4; ++rr) l[rr] += __shfl_xor(l[rr], off);
#pragma unroll
  for (int rr = 0; rr < 4; ++rr) l[rr] = 1.f / l[rr];

#pragma unroll
  for (int dt = 0; dt < 4; ++dt) {
#pragma unroll
    for (int rr = 0; rr < 4; ++rr) {
      const int qq = q0 + wid * 16 + fk * 4 + rr;
      ob[((size_t)qq * 4 + b) * 1024 + h * 64 + dt * 16 + fr] =
          f2bf(o4[dt][rr] * l[rr]);
    }
  }
}

// ---------------- LN2 + router + gate + final multiply ----------------
__global__ __launch_bounds__(256) void final_kernel(
    const float* __restrict__ xn, const float* __restrict__ w,
    const float* __restrict__ bb, const float* __restrict__ gw,
    float* __restrict__ out, float* __restrict__ rlog) {
  const int t = blockIdx.x, tid = threadIdx.x;
  const fx4 v = ((const fx4*)(xn + (size_t)t * D_DIM))[tid];
  float s  = v[0] + v[1] + v[2] + v[3];
  float ss = v[0]*v[0] + v[1]*v[1] + v[2]*v[2] + v[3]*v[3];
#pragma unroll
  for (int off = 32; off >= 1; off >>= 1) {
    s  += __shfl_xor(s, off);
    ss += __shfl_xor(ss, off);
  }
  __shared__ float red[8];
  __shared__ float red2[12];
  const int wid = tid >> 6, lane = tid & 63;
  if (lane == 0) { red[wid] = s; red[4 + wid] = ss; }
  __syncthreads();
  s  = red[0] + red[1] + red[2] + red[3];
  ss = red[4] + red[5] + red[6] + red[7];
  const float mu = s * (1.f / D_DIM);
  const float rstd = rsqrtf(ss * (1.f / D_DIM) - mu * mu + 1e-5f);
  const fx4 wv = ((const fx4*)w)[tid];
  const fx4 bv = ((const fx4*)bb)[tid];
  fx4 hv;
#pragma unroll
  for (int cc = 0; cc < 4; ++cc) hv[cc] = (v[cc] - mu) * rstd * wv[cc] + bv[cc];

  const fx4 w0 = ((const fx4*)(gw           ))[tid];
  const fx4 w1 = ((const fx4*)(gw +     D_DIM))[tid];
  const fx4 w2 = ((const fx4*)(gw + 2 * D_DIM))[tid];
  float g0 = hv[0]*w0[0] + hv[1]*w0[1] + hv[2]*w0[2] + hv[3]*w0[3];
  float g1 = hv[0]*w1[0] + hv[1]*w1[1] + hv[2]*w1[2] + hv[3]*w1[3];
  float g2 = hv[0]*w2[0] + hv[1]*w2[1] + hv[2]*w2[2] + hv[3]*w2[3];
#pragma unroll
  for (int off = 32; off >= 1; off >>= 1) {
    g0 += __shfl_xor(g0, off);
    g1 += __shfl_xor(g1, off);
    g2 += __shfl_xor(g2, off);
  }
  if (lane == 0) { red2[wid] = g0; red2[4 + wid] = g1; red2[8 + wid] = g2; }
  __syncthreads();
  g0 = red2[0] + red2[1] + red2[2]  + red2[3];
  g1 = red2[4] + red2[5] + red2[6]  + red2[7];
  g2 = red2[8] + red2[9] + red2[10] + red2[11];

  // gate = pmax/(pmax+p2nd) of softmax over 3 = 1/(1+exp(l_mid - l_max))
  const float lmax = fmaxf(g0, fmaxf(g1, g2));
  const float lmin = fminf(g0, fminf(g1, g2));
  const float lmid = (g0 + g1 + g2) - lmax - lmin;
  const float gate = 1.f / (1.f + __expf(lmid - lmax));

  ((fx4*)(out + (size_t)t * D_DIM))[tid] = v * gate;
  if (tid == 0) {
    rlog[(size_t)t * 3 + 0] = g0;
    rlog[(size_t)t * 3 + 1] = g1;
    rlog[(size_t)t * 3 + 2] = g2;
  }
}

extern "C" void kernel_launch(void* const* d_in, const int* in_sizes, int n_in,
                              void* d_out, int out_size, void* d_ws, size_t ws_size,
                              hipStream_t stream) {
  (void)in_sizes; (void)n_in; (void)out_size; (void)ws_size;
  const float* x    = (const float*)d_in[0];
  const float* ln1w = (const float*)d_in[1];
  const float* ln1b = (const float*)d_in[2];
  const float* ln2w = (const float*)d_in[3];
  const float* ln2b = (const float*)d_in[4];
  const float* win  = (const float*)d_in[5];
  const float* bin  = (const float*)d_in[6];
  const float* wout = (const float*)d_in[7];
  const float* bout = (const float*)d_in[8];
  const float* gw   = (const float*)d_in[9];
  // fc_w / fc_b / proj_w / proj_b (d_in[10..13]) are dead code in the reference.

  char* ws = (char*)d_ws;
  bf16*   w_in_b  = (bf16*)(ws);               // 6 MiB
  bf16*   w_out_b = (bf16*)(ws + 6291456);     // 2 MiB
  bf16*   h_b     = (bf16*)(ws + 8388608);     // 8 MiB (LN1 out; o_b aliases)
  ushort* o_b     = (ushort*)h_b;              // alias: h dead after GEMM1
  ushort* qkvb    = (ushort*)(ws + 16777216);  // 24 MiB: q/k/v bf16 [bh][s][64]
  ushort* q_b     = qkvb;
  ushort* k_b     = qkvb + 4194304;
  ushort* v_b     = qkvb + 8388608;
  float*  xnew    = (float*)(ws + 41943040);   // 16 MiB
  // total ws use: 56 MiB

  float* out  = (float*)d_out;
  float* rlog = out + (size_t)T_DIM * D_DIM;

  cast_f32_bf16<<<(3145728 / 4) / 256, 256, 0, stream>>>(win,  w_in_b,  3145728 / 4);
  cast_f32_bf16<<<(1048576 / 4) / 256, 256, 0, stream>>>(wout, w_out_b, 1048576 / 4);
  ln_bf16_kernel<<<T_DIM, 256, 0, stream>>>(x, ln1w, ln1b, h_b);
  gemm_bt<2><<<dim3(QKV_N / 128, T_DIM / 128), 256, 0, stream>>>(
      h_b, w_in_b, bin, nullptr, nullptr, qkvb, QKV_N, D_DIM);
  attn_mfma<<<1024, 256, 0, stream>>>(q_b, k_b, v_b, o_b);
  gemm_bt<1><<<dim3(D_DIM / 128, T_DIM / 128), 256, 0, stream>>>(
      (const bf16*)o_b, w_out_b, bout, x, xnew, nullptr, D_DIM, D_DIM);
  final_kernel<<<T_DIM, 256, 0, stream>>>(xnew, ln2w, ln2b, gw, out, rlog);
}

// Round 3
// 132.558 us; speedup vs baseline: 7.0752x; 1.0498x over previous
//
#include <hip/hip_runtime.h>
#include <hip/hip_bf16.h>

#define S_DIM 1024
#define B_DIM 4
#define D_DIM 1024
#define H_DIM 16
#define DH    64
#define T_DIM (S_DIM * B_DIM)   // 4096
#define QKV_N (3 * D_DIM)       // 3072

using bf16 = __hip_bfloat16;
typedef __attribute__((ext_vector_type(4))) float fx4;
typedef __attribute__((ext_vector_type(8))) short bx8;

__device__ __forceinline__ unsigned short f2bf(float f) {
  union { float f; unsigned int u; } cv; cv.f = f;
  unsigned int u = cv.u;
  unsigned int r = (u + 0x7FFFu + ((u >> 16) & 1u)) >> 16;  // RNE
  return (unsigned short)r;
}

__device__ __forceinline__ void g2l16(const void* g, void* l) {
  __builtin_amdgcn_global_load_lds(
      (const __attribute__((address_space(1))) unsigned int*)g,
      (__attribute__((address_space(3))) unsigned int*)l, 16, 0, 0);
}

// ---------------- fused weight cast fp32 -> bf16 ----------------
__global__ __launch_bounds__(256) void cast2_f32_bf16(
    const float* __restrict__ a, bf16* __restrict__ da, int an4,
    const float* __restrict__ b, bf16* __restrict__ db, int bn4) {
  const int i = blockIdx.x * 256 + threadIdx.x;
  const float* src; bf16* dst; int j;
  if (i < an4) { src = a; dst = da; j = i; }
  else if (i < an4 + bn4) { src = b; dst = db; j = i - an4; }
  else return;
  const fx4 v = ((const fx4*)src)[j];
  ushort4 u;
  u.x = f2bf(v[0]); u.y = f2bf(v[1]); u.z = f2bf(v[2]); u.w = f2bf(v[3]);
  ((ushort4*)dst)[j] = u;
}

// ---------------- LN (row of 1024) -> bf16 ----------------
__global__ __launch_bounds__(256) void ln_bf16_kernel(
    const float* __restrict__ x, const float* __restrict__ w,
    const float* __restrict__ bb, bf16* __restrict__ out) {
  const int t = blockIdx.x, tid = threadIdx.x;
  const fx4 v = ((const fx4*)(x + (size_t)t * D_DIM))[tid];
  float s  = v[0] + v[1] + v[2] + v[3];
  float ss = v[0]*v[0] + v[1]*v[1] + v[2]*v[2] + v[3]*v[3];
#pragma unroll
  for (int off = 32; off >= 1; off >>= 1) {
    s  += __shfl_xor(s, off);
    ss += __shfl_xor(ss, off);
  }
  __shared__ float red[8];
  const int wid = tid >> 6, lane = tid & 63;
  if (lane == 0) { red[wid] = s; red[4 + wid] = ss; }
  __syncthreads();
  s  = red[0] + red[1] + red[2] + red[3];
  ss = red[4] + red[5] + red[6] + red[7];
  const float mu = s * (1.f / D_DIM);
  const float rstd = rsqrtf(ss * (1.f / D_DIM) - mu * mu + 1e-5f);
  const fx4 wv = ((const fx4*)w)[tid];
  const fx4 bv = ((const fx4*)bb)[tid];
  ushort4 u;
  u.x = f2bf((v[0] - mu) * rstd * wv[0] + bv[0]);
  u.y = f2bf((v[1] - mu) * rstd * wv[1] + bv[1]);
  u.z = f2bf((v[2] - mu) * rstd * wv[2] + bv[2]);
  u.w = f2bf((v[3] - mu) * rstd * wv[3] + bv[3]);
  ((ushort4*)(out + (size_t)t * D_DIM))[tid] = u;
}

// ---------------- bf16 MFMA GEMM: C[M,N] = A[M,K] @ B[N,K]^T ----------------
// EPI 1: C(fp32) = acc + bias + resid.
// EPI 2: qkv split-write: bf16 to q/k/v [bh][s][64], q scaled by 0.125.
template <int EPI>
__global__ __launch_bounds__(256, 2) void gemm_bt(
    const bf16* __restrict__ A, const bf16* __restrict__ B,
    const float* __restrict__ bias, const float* __restrict__ resid,
    float* __restrict__ C, ushort* __restrict__ qkvb, int N, int K) {
  __shared__ bf16 sA[128 * 32];
  __shared__ bf16 sB[128 * 32];
  const int tid  = threadIdx.x;
  const int brow = blockIdx.y * 128;
  const int bcol = blockIdx.x * 128;
  const int wid  = tid >> 6;
  const int lane = tid & 63;
  const int wr   = wid >> 1;
  const int wc   = wid & 1;
  const int fr   = lane & 15;
  const int fk   = lane >> 4;

  fx4 acc[4][4];
#pragma unroll
  for (int i = 0; i < 4; ++i)
#pragma unroll
    for (int j = 0; j < 4; ++j) acc[i][j] = 0.f;

  const int arow = tid >> 2;
  const int acol = (tid & 3) * 8;

  for (int kt = 0; kt < K; kt += 32) {
    __syncthreads();
#pragma unroll
    for (int is = 0; is < 2; ++is) {
      const int row = is * 64 + arow;
      const int off = row * 64 + acol * 2;
      g2l16(A + (size_t)(brow + row) * K + kt + acol, (char*)sA + off);
      g2l16(B + (size_t)(bcol + row) * K + kt + acol, (char*)sB + off);
    }
    __syncthreads();

    bx8 af[4], bfr[4];
#pragma unroll
    for (int mm = 0; mm < 4; ++mm)
      af[mm] = *(const bx8*)(sA + (wr * 64 + mm * 16 + fr) * 32 + fk * 8);
#pragma unroll
    for (int nn = 0; nn < 4; ++nn)
      bfr[nn] = *(const bx8*)(sB + (wc * 64 + nn * 16 + fr) * 32 + fk * 8);
#pragma unroll
    for (int mm = 0; mm < 4; ++mm)
#pragma unroll
      for (int nn = 0; nn < 4; ++nn)
        acc[mm][nn] = __builtin_amdgcn_mfma_f32_16x16x32_bf16(
            af[mm], bfr[nn], acc[mm][nn], 0, 0, 0);
  }

  // C/D layout: col = lane&15, row = (lane>>4)*4 + reg
  const int row0 = brow + wr * 64 + fk * 4;
  const int col0 = bcol + wc * 64 + fr;
#pragma unroll
  for (int mm = 0; mm < 4; ++mm) {
#pragma unroll
    for (int nn = 0; nn < 4; ++nn) {
      const int col = col0 + nn * 16;
      const float bv = bias[col];
      if (EPI == 1) {
#pragma unroll
        for (int rr = 0; rr < 4; ++rr) {
          const int row = row0 + mm * 16 + rr;
          C[(size_t)row * N + col] = acc[mm][nn][rr] + bv + resid[(size_t)row * N + col];
        }
      } else {  // EPI == 2
        const int which = col >> 10;          // 0=q 1=k 2=v
        const int rem   = col & 1023;
        const int hh    = rem >> 6;
        const int dh    = rem & 63;
        const float scale = (which == 0) ? 0.125f : 1.0f;
#pragma unroll
        for (int rr = 0; rr < 4; ++rr) {
          const int row = row0 + mm * 16 + rr;  // t = s*B + b
          const int ss2 = row >> 2, bb2 = row & 3;
          const float v = (acc[mm][nn][rr] + bv) * scale;
          qkvb[(size_t)which * 4194304 +
               ((size_t)(bb2 * 16 + hh)) * 65536 + (size_t)ss2 * 64 + dh] = f2bf(v);
        }
      }
    }
  }
}

// ---------------- V [bh][s][64] -> V^T [bh][dh][1024] ----------------
__global__ __launch_bounds__(256) void transpose_v(
    const ushort* __restrict__ v, ushort* __restrict__ vt) {
  __shared__ ushort tile[64][65];
  const int g  = blockIdx.x;
  const int bh = g >> 4, st = g & 15;
  const int s0 = st * 64;
  const int tid = threadIdx.x;
  const int r  = tid >> 2;          // 0..63
  const int c0 = (tid & 3) * 16;    // 0,16,32,48
  const ushort* src = v + (size_t)bh * 65536 + (size_t)(s0 + r) * 64 + c0;
#pragma unroll
  for (int i = 0; i < 2; ++i) {
    const bx8 d = *(const bx8*)(src + i * 8);
#pragma unroll
    for (int j = 0; j < 8; ++j) tile[r][c0 + i * 8 + j] = (ushort)d[j];
  }
  __syncthreads();
  // write row dh=r, s range [s0+c0, s0+c0+16)
  ushort* dst = vt + (size_t)bh * 65536 + (size_t)r * 1024 + s0 + c0;
  bx8 w0, w1;
#pragma unroll
  for (int j = 0; j < 8; ++j) {
    w0[j] = (short)tile[c0 + j][r];
    w1[j] = (short)tile[c0 + 8 + j][r];
  }
  *(bx8*)dst = w0;
  *(bx8*)(dst + 8) = w1;
}

// ---------------- MFMA flash attention, 2-phase pipelined ----------------
// Block = (bh, q-tile of 64). 4 waves x 16 q-rows. 64-key blocks, causal.
// K and V^T double-buffered in LDS via global_load_lds with pre-swizzled
// source (byte ^= (row&7)<<4); next k-block staged before computing current;
// counted s_waitcnt vmcnt + raw s_barrier keep the prefetch in flight.
__global__ __launch_bounds__(256, 4) void attn_mfma(
    const ushort* __restrict__ qb, const ushort* __restrict__ kb,
    const ushort* __restrict__ vtb, ushort* __restrict__ ob) {
  __shared__ __align__(16) char sK[2][8192];
  __shared__ __align__(16) char sVT[2][8192];
  __shared__ __align__(16) char sP[8192];
  const int tid  = threadIdx.x;
  const int wid  = tid >> 6;
  const int lane = tid & 63;
  // pair q-tiles pr and 15-pr so consecutive blocks have equal causal work
  const int g  = blockIdx.x;
  const int u  = g >> 1;
  const int pr = u & 7;
  const int qt = (g & 1) ? (15 - pr) : pr;
  const int bh = u >> 3;
  const int b  = bh >> 4, h = bh & 15;
  const int q0 = qt * 64;
  const int fr = lane & 15;
  const int fk = lane >> 4;
  const size_t bhoff = (size_t)bh * 65536;

  // Q A-fragments (pre-scaled by DH^-0.5 upstream); drain so vmcnt counting
  // below sees only global_load_lds ops.
  const int qrow = q0 + wid * 16 + fr;
  const bx8 qf0 = *(const bx8*)(qb + bhoff + (size_t)qrow * 64 + fk * 8);
  const bx8 qf1 = *(const bx8*)(qb + bhoff + (size_t)qrow * 64 + 32 + fk * 8);
  asm volatile("s_waitcnt vmcnt(0)" ::: "memory");

  fx4 o4[4];
  float m[4], l[4];
#pragma unroll
  for (int dt = 0; dt < 4; ++dt) o4[dt] = 0.f;
#pragma unroll
  for (int rr = 0; rr < 4; ++rr) { m[rr] = -INFINITY; l[rr] = 0.f; }

  char* const sPw = sP + wid * 2048;

  auto stage = [&](int buf, int kbk) {
    const int k0 = kbk * 64;
#pragma unroll
    for (int is = 0; is < 2; ++is) {
      const int L    = is * 4096 + tid * 16;
      const int row  = L >> 7;
      const int colb = (L & 127) ^ ((row & 7) << 4);
      g2l16(kb  + bhoff + (size_t)(k0 + row) * 64 + (colb >> 1), sK[buf]  + L);
      g2l16(vtb + bhoff + (size_t)row * 1024 + k0 + (colb >> 1), sVT[buf] + L);
    }
  };

  stage(0, 0);
  int cur = 0;

  for (int kbk = 0; kbk <= qt; ++kbk) {
    const int k0 = kbk * 64;
    if (kbk < qt) {
      stage(cur ^ 1, kbk + 1);                      // prefetch next k-block
      asm volatile("s_waitcnt vmcnt(4)" ::: "memory");  // current buf landed
    } else {
      asm volatile("s_waitcnt vmcnt(0)" ::: "memory");
    }
    __builtin_amdgcn_s_barrier();
    asm volatile("" ::: "memory");
    const char* sKc  = sK[cur];
    const char* sVTc = sVT[cur];

    // --- S = Q K^T ---
    fx4 s4[4];
    __builtin_amdgcn_s_setprio(1);
#pragma unroll
    for (int kt = 0; kt < 4; ++kt) {
      const int krow = kt * 16 + fr;
      const int sw   = (krow & 7) << 4;
      const bx8 b0 = *(const bx8*)(sKc + krow * 128 + ((fk * 16) ^ sw));
      const bx8 b1 = *(const bx8*)(sKc + krow * 128 + ((64 + fk * 16) ^ sw));
      fx4 z = {0.f, 0.f, 0.f, 0.f};
      z = __builtin_amdgcn_mfma_f32_16x16x32_bf16(qf0, b0, z, 0, 0, 0);
      s4[kt] = __builtin_amdgcn_mfma_f32_16x16x32_bf16(qf1, b1, z, 0, 0, 0);
    }
    __builtin_amdgcn_s_setprio(0);

    if (kbk == qt) {  // diagonal block: causal mask
#pragma unroll
      for (int kt = 0; kt < 4; ++kt) {
        const int key = k0 + kt * 16 + fr;
#pragma unroll
        for (int rr = 0; rr < 4; ++rr) {
          const int qq = q0 + wid * 16 + fk * 4 + rr;
          if (key > qq) s4[kt][rr] = -INFINITY;
        }
      }
    }

    // --- online softmax (row = fk*4+rr, cols across 16-lane group) ---
    float pm[4];
#pragma unroll
    for (int rr = 0; rr < 4; ++rr)
      pm[rr] = fmaxf(fmaxf(s4[0][rr], s4[1][rr]), fmaxf(s4[2][rr], s4[3][rr]));
#pragma unroll
    for (int off = 1; off <= 8; off <<= 1)
#pragma unroll
      for (int rr = 0; rr < 4; ++rr)
        pm[rr] = fmaxf(pm[rr], __shfl_xor(pm[rr], off));

    // defer-max (T13): only rescale when max grew by > 8
    bool need = false;
#pragma unroll
    for (int rr = 0; rr < 4; ++rr) need = need || (pm[rr] > m[rr] + 8.f);
    if (__any(need)) {
#pragma unroll
      for (int rr = 0; rr < 4; ++rr) {
        const float mn = fmaxf(m[rr], pm[rr]);
        const float f  = __expf(m[rr] - mn);  // first iter: exp(-inf)=0
        m[rr] = mn;
        l[rr] *= f;
#pragma unroll
        for (int dt = 0; dt < 4; ++dt) o4[dt][rr] *= f;
      }
    }

#pragma unroll
    for (int kt = 0; kt < 4; ++kt) {
#pragma unroll
      for (int rr = 0; rr < 4; ++rr) {
        const float pv = __expf(s4[kt][rr] - m[rr]);
        l[rr] += pv;  // lane-partial row sum; cross-lane reduce at end
        const int qr = fk * 4 + rr;
        *(ushort*)(sPw + ((qr * 128 + (kt * 16 + fr) * 2) ^ ((qr & 7) << 4))) = f2bf(pv);
      }
    }

    // --- O += P V ---
    __builtin_amdgcn_s_setprio(1);
#pragma unroll
    for (int c = 0; c < 2; ++c) {
      const bx8 pa = *(const bx8*)(sPw + fr * 128 + ((c * 64 + fk * 16) ^ ((fr & 7) << 4)));
#pragma unroll
      for (int dt = 0; dt < 4; ++dt) {
        const int vrow = dt * 16 + fr;
        const bx8 vf = *(const bx8*)(sVTc + vrow * 128 + ((c * 64 + fk * 16) ^ ((vrow & 7) << 4)));
        o4[dt] = __builtin_amdgcn_mfma_f32_16x16x32_bf16(pa, vf, o4[dt], 0, 0, 0);
      }
    }
    __builtin_amdgcn_s_setprio(0);

    asm volatile("" ::: "memory");
    __builtin_amdgcn_s_barrier();   // readers done before next stage overwrite
    asm volatile("" ::: "memory");
    cur ^= 1;
  }

  // finish row sums, normalize, store
#pragma unroll
  for (int off = 1; off <= 8; off <<= 1)
#pragma unroll
    for (int rr = 0; rr < 4; ++rr) l[rr] += __shfl_xor(l[rr], off);
#pragma unroll
  for (int rr = 0; rr < 4; ++rr) l[rr] = 1.f / l[rr];

#pragma unroll
  for (int dt = 0; dt < 4; ++dt) {
#pragma unroll
    for (int rr = 0; rr < 4; ++rr) {
      const int qq = q0 + wid * 16 + fk * 4 + rr;
      ob[((size_t)qq * 4 + b) * 1024 + h * 64 + dt * 16 + fr] =
          f2bf(o4[dt][rr] * l[rr]);
    }
  }
}

// ---------------- LN2 + router + gate + final multiply ----------------
__global__ __launch_bounds__(256) void final_kernel(
    const float* __restrict__ xn, const float* __restrict__ w,
    const float* __restrict__ bb, const float* __restrict__ gw,
    float* __restrict__ out, float* __restrict__ rlog) {
  const int t = blockIdx.x, tid = threadIdx.x;
  const fx4 v = ((const fx4*)(xn + (size_t)t * D_DIM))[tid];
  float s  = v[0] + v[1] + v[2] + v[3];
  float ss = v[0]*v[0] + v[1]*v[1] + v[2]*v[2] + v[3]*v[3];
#pragma unroll
  for (int off = 32; off >= 1; off >>= 1) {
    s  += __shfl_xor(s, off);
    ss += __shfl_xor(ss, off);
  }
  __shared__ float red[8];
  __shared__ float red2[12];
  const int wid = tid >> 6, lane = tid & 63;
  if (lane == 0) { red[wid] = s; red[4 + wid] = ss; }
  __syncthreads();
  s  = red[0] + red[1] + red[2] + red[3];
  ss = red[4] + red[5] + red[6] + red[7];
  const float mu = s * (1.f / D_DIM);
  const float rstd = rsqrtf(ss * (1.f / D_DIM) - mu * mu + 1e-5f);
  const fx4 wv = ((const fx4*)w)[tid];
  const fx4 bv = ((const fx4*)bb)[tid];
  fx4 hv;
#pragma unroll
  for (int cc = 0; cc < 4; ++cc) hv[cc] = (v[cc] - mu) * rstd * wv[cc] + bv[cc];

  const fx4 w0 = ((const fx4*)(gw           ))[tid];
  const fx4 w1 = ((const fx4*)(gw +     D_DIM))[tid];
  const fx4 w2 = ((const fx4*)(gw + 2 * D_DIM))[tid];
  float g0 = hv[0]*w0[0] + hv[1]*w0[1] + hv[2]*w0[2] + hv[3]*w0[3];
  float g1 = hv[0]*w1[0] + hv[1]*w1[1] + hv[2]*w1[2] + hv[3]*w1[3];
  float g2 = hv[0]*w2[0] + hv[1]*w2[1] + hv[2]*w2[2] + hv[3]*w2[3];
#pragma unroll
  for (int off = 32; off >= 1; off >>= 1) {
    g0 += __shfl_xor(g0, off);
    g1 += __shfl_xor(g1, off);
    g2 += __shfl_xor(g2, off);
  }
  if (lane == 0) { red2[wid] = g0; red2[4 + wid] = g1; red2[8 + wid] = g2; }
  __syncthreads();
  g0 = red2[0] + red2[1] + red2[2]  + red2[3];
  g1 = red2[4] + red2[5] + red2[6]  + red2[7];
  g2 = red2[8] + red2[9] + red2[10] + red2[11];

  // gate = pmax/(pmax+p2nd) of softmax over 3 = 1/(1+exp(l_mid - l_max))
  const float lmax = fmaxf(g0, fmaxf(g1, g2));
  const float lmin = fminf(g0, fminf(g1, g2));
  const float lmid = (g0 + g1 + g2) - lmax - lmin;
  const float gate = 1.f / (1.f + __expf(lmid - lmax));

  ((fx4*)(out + (size_t)t * D_DIM))[tid] = v * gate;
  if (tid == 0) {
    rlog[(size_t)t * 3 + 0] = g0;
    rlog[(size_t)t * 3 + 1] = g1;
    rlog[(size_t)t * 3 + 2] = g2;
  }
}

extern "C" void kernel_launch(void* const* d_in, const int* in_sizes, int n_in,
                              void* d_out, int out_size, void* d_ws, size_t ws_size,
                              hipStream_t stream) {
  (void)in_sizes; (void)n_in; (void)out_size; (void)ws_size;
  const float* x    = (const float*)d_in[0];
  const float* ln1w = (const float*)d_in[1];
  const float* ln1b = (const float*)d_in[2];
  const float* ln2w = (const float*)d_in[3];
  const float* ln2b = (const float*)d_in[4];
  const float* win  = (const float*)d_in[5];
  const float* bin  = (const float*)d_in[6];
  const float* wout = (const float*)d_in[7];
  const float* bout = (const float*)d_in[8];
  const float* gw   = (const float*)d_in[9];
  // fc_w / fc_b / proj_w / proj_b (d_in[10..13]) are dead code in the reference.

  char* ws = (char*)d_ws;
  bf16*   w_in_b  = (bf16*)(ws);               // 6 MiB
  bf16*   w_out_b = (bf16*)(ws + 6291456);     // 2 MiB
  bf16*   h_b     = (bf16*)(ws + 8388608);     // 8 MiB (LN1 out; o_b aliases)
  ushort* o_b     = (ushort*)h_b;              // alias: h dead after GEMM1
  ushort* qkvb    = (ushort*)(ws + 16777216);  // 24 MiB: q/k/v bf16 [bh][s][64]
  ushort* q_b     = qkvb;
  ushort* k_b     = qkvb + 4194304;
  ushort* v_b     = qkvb + 8388608;
  float*  xnew    = (float*)(ws + 41943040);   // 16 MiB
  ushort* vt_b    = (ushort*)(ws + 58720256);  // 8 MiB: V^T [bh][dh][s]
  // total ws use: 64 MiB

  float* out  = (float*)d_out;
  float* rlog = out + (size_t)T_DIM * D_DIM;

  cast2_f32_bf16<<<4096, 256, 0, stream>>>(win, w_in_b, 786432,
                                           wout, w_out_b, 262144);
  ln_bf16_kernel<<<T_DIM, 256, 0, stream>>>(x, ln1w, ln1b, h_b);
  gemm_bt<2><<<dim3(QKV_N / 128, T_DIM / 128), 256, 0, stream>>>(
      h_b, w_in_b, bin, nullptr, nullptr, qkvb, QKV_N, D_DIM);
  transpose_v<<<1024, 256, 0, stream>>>(v_b, vt_b);
  attn_mfma<<<1024, 256, 0, stream>>>(q_b, k_b, vt_b, o_b);
  gemm_bt<1><<<dim3(D_DIM / 128, T_DIM / 128), 256, 0, stream>>>(
      (const bf16*)o_b, w_out_b, bout, x, xnew, nullptr, D_DIM, D_DIM);
  final_kernel<<<T_DIM, 256, 0, stream>>>(xnew, ln2w, ln2b, gw, out, rlog);
}

// Round 4
// 118.466 us; speedup vs baseline: 7.9167x; 1.1189x over previous
//
#include <hip/hip_runtime.h>
#include <hip/hip_bf16.h>

#define S_DIM 1024
#define B_DIM 4
#define D_DIM 1024
#define H_DIM 16
#define DH    64
#define T_DIM (S_DIM * B_DIM)   // 4096
#define QKV_N (3 * D_DIM)       // 3072

using bf16 = __hip_bfloat16;
typedef __attribute__((ext_vector_type(4))) float fx4;
typedef __attribute__((ext_vector_type(8))) short bx8;

__device__ __forceinline__ unsigned short f2bf(float f) {
  union { float f; unsigned int u; } cv; cv.f = f;
  unsigned int u = cv.u;
  unsigned int r = (u + 0x7FFFu + ((u >> 16) & 1u)) >> 16;  // RNE
  return (unsigned short)r;
}

__device__ __forceinline__ void g2l16(const void* g, void* l) {
  __builtin_amdgcn_global_load_lds(
      (const __attribute__((address_space(1))) unsigned int*)g,
      (__attribute__((address_space(3))) unsigned int*)l, 16, 0, 0);
}

// ---------------- fused weight cast fp32 -> bf16 ----------------
__global__ __launch_bounds__(256) void cast2_f32_bf16(
    const float* __restrict__ a, bf16* __restrict__ da, int an4,
    const float* __restrict__ b, bf16* __restrict__ db, int bn4) {
  const int i = blockIdx.x * 256 + threadIdx.x;
  const float* src; bf16* dst; int j;
  if (i < an4) { src = a; dst = da; j = i; }
  else if (i < an4 + bn4) { src = b; dst = db; j = i - an4; }
  else return;
  const fx4 v = ((const fx4*)src)[j];
  ushort4 u;
  u.x = f2bf(v[0]); u.y = f2bf(v[1]); u.z = f2bf(v[2]); u.w = f2bf(v[3]);
  ((ushort4*)dst)[j] = u;
}

// ---------------- LN (row of 1024) -> bf16 ----------------
__global__ __launch_bounds__(256) void ln_bf16_kernel(
    const float* __restrict__ x, const float* __restrict__ w,
    const float* __restrict__ bb, bf16* __restrict__ out) {
  const int t = blockIdx.x, tid = threadIdx.x;
  const fx4 v = ((const fx4*)(x + (size_t)t * D_DIM))[tid];
  float s  = v[0] + v[1] + v[2] + v[3];
  float ss = v[0]*v[0] + v[1]*v[1] + v[2]*v[2] + v[3]*v[3];
#pragma unroll
  for (int off = 32; off >= 1; off >>= 1) {
    s  += __shfl_xor(s, off);
    ss += __shfl_xor(ss, off);
  }
  __shared__ float red[8];
  const int wid = tid >> 6, lane = tid & 63;
  if (lane == 0) { red[wid] = s; red[4 + wid] = ss; }
  __syncthreads();
  s  = red[0] + red[1] + red[2] + red[3];
  ss = red[4] + red[5] + red[6] + red[7];
  const float mu = s * (1.f / D_DIM);
  const float rstd = rsqrtf(ss * (1.f / D_DIM) - mu * mu + 1e-5f);
  const fx4 wv = ((const fx4*)w)[tid];
  const fx4 bv = ((const fx4*)bb)[tid];
  ushort4 u;
  u.x = f2bf((v[0] - mu) * rstd * wv[0] + bv[0]);
  u.y = f2bf((v[1] - mu) * rstd * wv[1] + bv[1]);
  u.z = f2bf((v[2] - mu) * rstd * wv[2] + bv[2]);
  u.w = f2bf((v[3] - mu) * rstd * wv[3] + bv[3]);
  ((ushort4*)(out + (size_t)t * D_DIM))[tid] = u;
}

// ---------------- bf16 MFMA GEMM: C[M,N] = A[M,K] @ B[N,K]^T ----------------
// EPI 1: C(fp32) = acc + bias + resid.
// EPI 2: qkv split-write: bf16 to q/k/v [bh][s][64], q scaled by 0.125.
template <int EPI>
__global__ __launch_bounds__(256, 2) void gemm_bt(
    const bf16* __restrict__ A, const bf16* __restrict__ B,
    const float* __restrict__ bias, const float* __restrict__ resid,
    float* __restrict__ C, ushort* __restrict__ qkvb, int N, int K) {
  __shared__ bf16 sA[128 * 32];
  __shared__ bf16 sB[128 * 32];
  const int tid  = threadIdx.x;
  const int brow = blockIdx.y * 128;
  const int bcol = blockIdx.x * 128;
  const int wid  = tid >> 6;
  const int lane = tid & 63;
  const int wr   = wid >> 1;
  const int wc   = wid & 1;
  const int fr   = lane & 15;
  const int fk   = lane >> 4;

  fx4 acc[4][4];
#pragma unroll
  for (int i = 0; i < 4; ++i)
#pragma unroll
    for (int j = 0; j < 4; ++j) acc[i][j] = 0.f;

  const int arow = tid >> 2;
  const int acol = (tid & 3) * 8;

  for (int kt = 0; kt < K; kt += 32) {
    __syncthreads();
#pragma unroll
    for (int is = 0; is < 2; ++is) {
      const int row = is * 64 + arow;
      const int off = row * 64 + acol * 2;
      g2l16(A + (size_t)(brow + row) * K + kt + acol, (char*)sA + off);
      g2l16(B + (size_t)(bcol + row) * K + kt + acol, (char*)sB + off);
    }
    __syncthreads();

    bx8 af[4], bfr[4];
#pragma unroll
    for (int mm = 0; mm < 4; ++mm)
      af[mm] = *(const bx8*)(sA + (wr * 64 + mm * 16 + fr) * 32 + fk * 8);
#pragma unroll
    for (int nn = 0; nn < 4; ++nn)
      bfr[nn] = *(const bx8*)(sB + (wc * 64 + nn * 16 + fr) * 32 + fk * 8);
#pragma unroll
    for (int mm = 0; mm < 4; ++mm)
#pragma unroll
      for (int nn = 0; nn < 4; ++nn)
        acc[mm][nn] = __builtin_amdgcn_mfma_f32_16x16x32_bf16(
            af[mm], bfr[nn], acc[mm][nn], 0, 0, 0);
  }

  // C/D layout: col = lane&15, row = (lane>>4)*4 + reg
  const int row0 = brow + wr * 64 + fk * 4;
  const int col0 = bcol + wc * 64 + fr;
#pragma unroll
  for (int mm = 0; mm < 4; ++mm) {
#pragma unroll
    for (int nn = 0; nn < 4; ++nn) {
      const int col = col0 + nn * 16;
      const float bv = bias[col];
      if (EPI == 1) {
#pragma unroll
        for (int rr = 0; rr < 4; ++rr) {
          const int row = row0 + mm * 16 + rr;
          C[(size_t)row * N + col] = acc[mm][nn][rr] + bv + resid[(size_t)row * N + col];
        }
      } else {  // EPI == 2
        const int which = col >> 10;          // 0=q 1=k 2=v
        const int rem   = col & 1023;
        const int hh    = rem >> 6;
        const int dh    = rem & 63;
        const float scale = (which == 0) ? 0.125f : 1.0f;
#pragma unroll
        for (int rr = 0; rr < 4; ++rr) {
          const int row = row0 + mm * 16 + rr;  // t = s*B + b
          const int ss2 = row >> 2, bb2 = row & 3;
          const float v = (acc[mm][nn][rr] + bv) * scale;
          qkvb[(size_t)which * 4194304 +
               ((size_t)(bb2 * 16 + hh)) * 65536 + (size_t)ss2 * 64 + dh] = f2bf(v);
        }
      }
    }
  }
}

// ---------------- V [bh][s][64] -> V^T [bh][dh][1024] ----------------
__global__ __launch_bounds__(256) void transpose_v(
    const ushort* __restrict__ v, ushort* __restrict__ vt) {
  __shared__ ushort tile[64][65];
  const int g  = blockIdx.x;
  const int bh = g >> 4, st = g & 15;
  const int s0 = st * 64;
  const int tid = threadIdx.x;
  const int r  = tid >> 2;          // 0..63
  const int c0 = (tid & 3) * 16;    // 0,16,32,48
  const ushort* src = v + (size_t)bh * 65536 + (size_t)(s0 + r) * 64 + c0;
#pragma unroll
  for (int i = 0; i < 2; ++i) {
    const bx8 d = *(const bx8*)(src + i * 8);
#pragma unroll
    for (int j = 0; j < 8; ++j) tile[r][c0 + i * 8 + j] = (ushort)d[j];
  }
  __syncthreads();
  // write row dh=r, s range [s0+c0, s0+c0+16)
  ushort* dst = vt + (size_t)bh * 65536 + (size_t)r * 1024 + s0 + c0;
  bx8 w0, w1;
#pragma unroll
  for (int j = 0; j < 8; ++j) {
    w0[j] = (short)tile[c0 + j][r];
    w1[j] = (short)tile[c0 + 8 + j][r];
  }
  *(bx8*)dst = w0;
  *(bx8*)(dst + 8) = w1;
}

// ---------------- MFMA flash attention, swapped-QK^T, balanced ----------------
// Block = bh x tile-pair {pr, 15-pr}: every block does exactly 17 k-iters.
// 4 waves x 16 q-rows per tile. Swapped S^T = mfma(K,Q): lane owns q = fr,
// 16 key-scores in regs -> 2-shfl row max, packed b64 P writes. 2-phase
// pipelined LDS (counted vmcnt, raw barriers), defer-max, setprio.
__global__ __launch_bounds__(256, 4) void attn_mfma(
    const ushort* __restrict__ qb, const ushort* __restrict__ kb,
    const ushort* __restrict__ vtb, ushort* __restrict__ ob) {
  __shared__ __align__(16) char sK[2][8192];
  __shared__ __align__(16) char sVT[2][8192];
  __shared__ __align__(16) char sP[8192];
  const int tid  = threadIdx.x;
  const int wid  = tid >> 6;
  const int lane = tid & 63;
  const int g    = blockIdx.x;
  const int bh   = g >> 3;
  const int pr   = g & 7;
  const int b    = bh >> 4, h = bh & 15;
  const int fr   = lane & 15;
  const int fk   = lane >> 4;
  const size_t bhoff = (size_t)bh * 65536;
  char* const sPw = sP + wid * 2048;
  const int swp = (fr & 7) << 4;   // P/row swizzle for this lane's q-row

  auto stage = [&](int buf, int k0) {
#pragma unroll
    for (int is = 0; is < 2; ++is) {
      const int L    = is * 4096 + tid * 16;
      const int row  = L >> 7;
      const int colb = (L & 127) ^ ((row & 7) << 4);
      g2l16(kb  + bhoff + (size_t)(k0 + row) * 64 + (colb >> 1), sK[buf]  + L);
      g2l16(vtb + bhoff + (size_t)row * 1024 + k0 + (colb >> 1), sVT[buf] + L);
    }
  };

#pragma unroll 1
  for (int tile = 0; tile < 2; ++tile) {
    const int qt  = tile ? (15 - pr) : pr;
    const int q0w = qt * 64 + wid * 16;

    const ushort* qp = qb + bhoff + (size_t)(q0w + fr) * 64;
    const bx8 qf0 = *(const bx8*)(qp + fk * 8);
    const bx8 qf1 = *(const bx8*)(qp + 32 + fk * 8);

    fx4 o4[4];
    float m = -3e38f, l = 0.f;
#pragma unroll
    for (int dt = 0; dt < 4; ++dt) o4[dt] = 0.f;

    stage(0, 0);
    asm volatile("s_waitcnt vmcnt(0)" ::: "memory");
    int cur = 0;

#pragma unroll 1
    for (int kbk = 0; kbk <= qt; ++kbk) {
      if (kbk < qt) {
        stage(cur ^ 1, (kbk + 1) * 64);                   // prefetch next
        asm volatile("s_waitcnt vmcnt(4)" ::: "memory");  // cur landed
      } else {
        asm volatile("s_waitcnt vmcnt(0)" ::: "memory");
      }
      __builtin_amdgcn_s_barrier();
      asm volatile("" ::: "memory");
      const char* sKc  = sK[cur];
      const char* sVTc = sVT[cur];

      // --- S^T = mfma(K, Q): s4[kt][rr] = S[key=kt*16+fk*4+rr][q=fr] ---
      fx4 s4[4];
      __builtin_amdgcn_s_setprio(1);
#pragma unroll
      for (int kt = 0; kt < 4; ++kt) {
        const int krow = kt * 16 + fr;
        const int sw   = (krow & 7) << 4;
        const bx8 kf0 = *(const bx8*)(sKc + krow * 128 + ((fk * 16) ^ sw));
        const bx8 kf1 = *(const bx8*)(sKc + krow * 128 + ((64 + fk * 16) ^ sw));
        fx4 z = {0.f, 0.f, 0.f, 0.f};
        z = __builtin_amdgcn_mfma_f32_16x16x32_bf16(kf0, qf0, z, 0, 0, 0);
        s4[kt] = __builtin_amdgcn_mfma_f32_16x16x32_bf16(kf1, qf1, z, 0, 0, 0);
      }
      __builtin_amdgcn_s_setprio(0);

      if (kbk == qt) {  // diagonal: mask key-local > q-local (wave-relative)
        const int qloc = wid * 16 + fr;
#pragma unroll
        for (int kt = 0; kt < 4; ++kt) {
          const int keyb = kt * 16 + fk * 4;
#pragma unroll
          for (int rr = 0; rr < 4; ++rr)
            if (keyb + rr > qloc) s4[kt][rr] = -3e38f;
        }
      }

      // --- online softmax: lane owns q=fr; keys split across fk group ---
      float pm = s4[0][0];
#pragma unroll
      for (int kt = 0; kt < 4; ++kt)
#pragma unroll
        for (int rr = 0; rr < 4; ++rr) pm = fmaxf(pm, s4[kt][rr]);
      pm = fmaxf(pm, __shfl_xor(pm, 16));
      pm = fmaxf(pm, __shfl_xor(pm, 32));

      if (__any(pm > m + 8.f)) {   // defer-max (T13)
        const float mn = fmaxf(m, pm);
        const float f  = __expf(m - mn);
        m = mn;
        l *= f;
        float fq[4];
#pragma unroll
        for (int rr = 0; rr < 4; ++rr) fq[rr] = __shfl(f, fk * 4 + rr);
#pragma unroll
        for (int dt = 0; dt < 4; ++dt)
#pragma unroll
          for (int rr = 0; rr < 4; ++rr) o4[dt][rr] *= fq[rr];
      }

      // --- P = exp(S-m), packed b64 writes: P[q=fr][k consecutive] ---
#pragma unroll
      for (int kt = 0; kt < 4; ++kt) {
        const float p0 = __expf(s4[kt][0] - m);
        const float p1 = __expf(s4[kt][1] - m);
        const float p2 = __expf(s4[kt][2] - m);
        const float p3 = __expf(s4[kt][3] - m);
        l += (p0 + p1) + (p2 + p3);
        uint2 pk;
        pk.x = ((unsigned)f2bf(p0)) | (((unsigned)f2bf(p1)) << 16);
        pk.y = ((unsigned)f2bf(p2)) | (((unsigned)f2bf(p3)) << 16);
        *(uint2*)(sPw + ((fr * 128 + kt * 32 + fk * 8) ^ swp)) = pk;
      }

      // --- O += P V ---
      __builtin_amdgcn_s_setprio(1);
#pragma unroll
      for (int c = 0; c < 2; ++c) {
        const bx8 pa = *(const bx8*)(sPw + ((fr * 128 + c * 64 + fk * 16) ^ swp));
#pragma unroll
        for (int dt = 0; dt < 4; ++dt) {
          const int vrow = dt * 16 + fr;
          const bx8 vf = *(const bx8*)(sVTc + vrow * 128 +
                                       ((c * 64 + fk * 16) ^ ((vrow & 7) << 4)));
          o4[dt] = __builtin_amdgcn_mfma_f32_16x16x32_bf16(pa, vf, o4[dt], 0, 0, 0);
        }
      }
      __builtin_amdgcn_s_setprio(0);

      asm volatile("" ::: "memory");
      __builtin_amdgcn_s_barrier();   // readers done before next overwrite
      asm volatile("" ::: "memory");
      cur ^= 1;
    }

    // --- epilogue: total row sums, fetch per-output-row norms, store ---
    l += __shfl_xor(l, 16);
    l += __shfl_xor(l, 32);
    const float linv = 1.f / l;
    float lq[4];
#pragma unroll
    for (int rr = 0; rr < 4; ++rr) lq[rr] = __shfl(linv, fk * 4 + rr);

#pragma unroll
    for (int dt = 0; dt < 4; ++dt) {
#pragma unroll
      for (int rr = 0; rr < 4; ++rr) {
        const int qq = q0w + fk * 4 + rr;
        ob[((size_t)qq * 4 + b) * 1024 + h * 64 + dt * 16 + fr] =
            f2bf(o4[dt][rr] * lq[rr]);
      }
    }
  }
}

// ---------------- LN2 + router + gate + final multiply ----------------
__global__ __launch_bounds__(256) void final_kernel(
    const float* __restrict__ xn, const float* __restrict__ w,
    const float* __restrict__ bb, const float* __restrict__ gw,
    float* __restrict__ out, float* __restrict__ rlog) {
  const int t = blockIdx.x, tid = threadIdx.x;
  const fx4 v = ((const fx4*)(xn + (size_t)t * D_DIM))[tid];
  float s  = v[0] + v[1] + v[2] + v[3];
  float ss = v[0]*v[0] + v[1]*v[1] + v[2]*v[2] + v[3]*v[3];
#pragma unroll
  for (int off = 32; off >= 1; off >>= 1) {
    s  += __shfl_xor(s, off);
    ss += __shfl_xor(ss, off);
  }
  __shared__ float red[8];
  __shared__ float red2[12];
  const int wid = tid >> 6, lane = tid & 63;
  if (lane == 0) { red[wid] = s; red[4 + wid] = ss; }
  __syncthreads();
  s  = red[0] + red[1] + red[2] + red[3];
  ss = red[4] + red[5] + red[6] + red[7];
  const float mu = s * (1.f / D_DIM);
  const float rstd = rsqrtf(ss * (1.f / D_DIM) - mu * mu + 1e-5f);
  const fx4 wv = ((const fx4*)w)[tid];
  const fx4 bv = ((const fx4*)bb)[tid];
  fx4 hv;
#pragma unroll
  for (int cc = 0; cc < 4; ++cc) hv[cc] = (v[cc] - mu) * rstd * wv[cc] + bv[cc];

  const fx4 w0 = ((const fx4*)(gw           ))[tid];
  const fx4 w1 = ((const fx4*)(gw +     D_DIM))[tid];
  const fx4 w2 = ((const fx4*)(gw + 2 * D_DIM))[tid];
  float g0 = hv[0]*w0[0] + hv[1]*w0[1] + hv[2]*w0[2] + hv[3]*w0[3];
  float g1 = hv[0]*w1[0] + hv[1]*w1[1] + hv[2]*w1[2] + hv[3]*w1[3];
  float g2 = hv[0]*w2[0] + hv[1]*w2[1] + hv[2]*w2[2] + hv[3]*w2[3];
#pragma unroll
  for (int off = 32; off >= 1; off >>= 1) {
    g0 += __shfl_xor(g0, off);
    g1 += __shfl_xor(g1, off);
    g2 += __shfl_xor(g2, off);
  }
  if (lane == 0) { red2[wid] = g0; red2[4 + wid] = g1; red2[8 + wid] = g2; }
  __syncthreads();
  g0 = red2[0] + red2[1] + red2[2]  + red2[3];
  g1 = red2[4] + red2[5] + red2[6]  + red2[7];
  g2 = red2[8] + red2[9] + red2[10] + red2[11];

  // gate = pmax/(pmax+p2nd) of softmax over 3 = 1/(1+exp(l_mid - l_max))
  const float lmax = fmaxf(g0, fmaxf(g1, g2));
  const float lmin = fminf(g0, fminf(g1, g2));
  const float lmid = (g0 + g1 + g2) - lmax - lmin;
  const float gate = 1.f / (1.f + __expf(lmid - lmax));

  ((fx4*)(out + (size_t)t * D_DIM))[tid] = v * gate;
  if (tid == 0) {
    rlog[(size_t)t * 3 + 0] = g0;
    rlog[(size_t)t * 3 + 1] = g1;
    rlog[(size_t)t * 3 + 2] = g2;
  }
}

extern "C" void kernel_launch(void* const* d_in, const int* in_sizes, int n_in,
                              void* d_out, int out_size, void* d_ws, size_t ws_size,
                              hipStream_t stream) {
  (void)in_sizes; (void)n_in; (void)out_size; (void)ws_size;
  const float* x    = (const float*)d_in[0];
  const float* ln1w = (const float*)d_in[1];
  const float* ln1b = (const float*)d_in[2];
  const float* ln2w = (const float*)d_in[3];
  const float* ln2b = (const float*)d_in[4];
  const float* win  = (const float*)d_in[5];
  const float* bin  = (const float*)d_in[6];
  const float* wout = (const float*)d_in[7];
  const float* bout = (const float*)d_in[8];
  const float* gw   = (const float*)d_in[9];
  // fc_w / fc_b / proj_w / proj_b (d_in[10..13]) are dead code in the reference.

  char* ws = (char*)d_ws;
  bf16*   w_in_b  = (bf16*)(ws);               // 6 MiB
  bf16*   w_out_b = (bf16*)(ws + 6291456);     // 2 MiB
  bf16*   h_b     = (bf16*)(ws + 8388608);     // 8 MiB (LN1 out; o_b aliases)
  ushort* o_b     = (ushort*)h_b;              // alias: h dead after GEMM1
  ushort* qkvb    = (ushort*)(ws + 16777216);  // 24 MiB: q/k/v bf16 [bh][s][64]
  ushort* q_b     = qkvb;
  ushort* k_b     = qkvb + 4194304;
  ushort* v_b     = qkvb + 8388608;
  float*  xnew    = (float*)(ws + 41943040);   // 16 MiB
  ushort* vt_b    = (ushort*)(ws + 58720256);  // 8 MiB: V^T [bh][dh][s]
  // total ws use: 64 MiB

  float* out  = (float*)d_out;
  float* rlog = out + (size_t)T_DIM * D_DIM;

  cast2_f32_bf16<<<4096, 256, 0, stream>>>(win, w_in_b, 786432,
                                           wout, w_out_b, 262144);
  ln_bf16_kernel<<<T_DIM, 256, 0, stream>>>(x, ln1w, ln1b, h_b);
  gemm_bt<2><<<dim3(QKV_N / 128, T_DIM / 128), 256, 0, stream>>>(
      h_b, w_in_b, bin, nullptr, nullptr, qkvb, QKV_N, D_DIM);
  transpose_v<<<1024, 256, 0, stream>>>(v_b, vt_b);
  attn_mfma<<<512, 256, 0, stream>>>(q_b, k_b, vt_b, o_b);
  gemm_bt<1><<<dim3(D_DIM / 128, T_DIM / 128), 256, 0, stream>>>(
      (const bf16*)o_b, w_out_b, bout, x, xnew, nullptr, D_DIM, D_DIM);
  final_kernel<<<T_DIM, 256, 0, stream>>>(xnew, ln2w, ln2b, gw, out, rlog);
}

// Round 5
// 115.849 us; speedup vs baseline: 8.0956x; 1.0226x over previous
//
#include <hip/hip_runtime.h>
#include <hip/hip_bf16.h>

#define S_DIM 1024
#define B_DIM 4
#define D_DIM 1024
#define H_DIM 16
#define DH    64
#define T_DIM (S_DIM * B_DIM)   // 4096
#define QKV_N (3 * D_DIM)       // 3072

using bf16 = __hip_bfloat16;
typedef __attribute__((ext_vector_type(4))) float fx4;
typedef __attribute__((ext_vector_type(8))) short bx8;

__device__ __forceinline__ unsigned short f2bf(float f) {
  union { float f; unsigned int u; } cv; cv.f = f;
  unsigned int u = cv.u;
  unsigned int r = (u + 0x7FFFu + ((u >> 16) & 1u)) >> 16;  // RNE
  return (unsigned short)r;
}

__device__ __forceinline__ void g2l16(const void* g, void* l) {
  __builtin_amdgcn_global_load_lds(
      (const __attribute__((address_space(1))) unsigned int*)g,
      (__attribute__((address_space(3))) unsigned int*)l, 16, 0, 0);
}

// ---------------- fused weight cast fp32 -> bf16 ----------------
__global__ __launch_bounds__(256) void cast2_f32_bf16(
    const float* __restrict__ a, bf16* __restrict__ da, int an4,
    const float* __restrict__ b, bf16* __restrict__ db, int bn4) {
  const int i = blockIdx.x * 256 + threadIdx.x;
  const float* src; bf16* dst; int j;
  if (i < an4) { src = a; dst = da; j = i; }
  else if (i < an4 + bn4) { src = b; dst = db; j = i - an4; }
  else return;
  const fx4 v = ((const fx4*)src)[j];
  ushort4 u;
  u.x = f2bf(v[0]); u.y = f2bf(v[1]); u.z = f2bf(v[2]); u.w = f2bf(v[3]);
  ((ushort4*)dst)[j] = u;
}

// ---------------- LN (row of 1024) -> bf16 ----------------
__global__ __launch_bounds__(256) void ln_bf16_kernel(
    const float* __restrict__ x, const float* __restrict__ w,
    const float* __restrict__ bb, bf16* __restrict__ out) {
  const int t = blockIdx.x, tid = threadIdx.x;
  const fx4 v = ((const fx4*)(x + (size_t)t * D_DIM))[tid];
  float s  = v[0] + v[1] + v[2] + v[3];
  float ss = v[0]*v[0] + v[1]*v[1] + v[2]*v[2] + v[3]*v[3];
#pragma unroll
  for (int off = 32; off >= 1; off >>= 1) {
    s  += __shfl_xor(s, off);
    ss += __shfl_xor(ss, off);
  }
  __shared__ float red[8];
  const int wid = tid >> 6, lane = tid & 63;
  if (lane == 0) { red[wid] = s; red[4 + wid] = ss; }
  __syncthreads();
  s  = red[0] + red[1] + red[2] + red[3];
  ss = red[4] + red[5] + red[6] + red[7];
  const float mu = s * (1.f / D_DIM);
  const float rstd = rsqrtf(ss * (1.f / D_DIM) - mu * mu + 1e-5f);
  const fx4 wv = ((const fx4*)w)[tid];
  const fx4 bv = ((const fx4*)bb)[tid];
  ushort4 u;
  u.x = f2bf((v[0] - mu) * rstd * wv[0] + bv[0]);
  u.y = f2bf((v[1] - mu) * rstd * wv[1] + bv[1]);
  u.z = f2bf((v[2] - mu) * rstd * wv[2] + bv[2]);
  u.w = f2bf((v[3] - mu) * rstd * wv[3] + bv[3]);
  ((ushort4*)(out + (size_t)t * D_DIM))[tid] = u;
}

// ---------------- bf16 MFMA GEMM: C[M,N] = A[M,K] @ B[N,K]^T ----------------
// T3-minimum 2-phase: double-buffered LDS, stage-next issued before compute,
// one vmcnt(0)+s_barrier per K-step. EPI 1: C = acc+bias+resid (fp32).
// EPI 2: qkv split-write bf16 [bh][s][64]; q pre-scaled by 0.125*log2(e).
template <int EPI>
__global__ __launch_bounds__(256, 2) void gemm_bt(
    const bf16* __restrict__ A, const bf16* __restrict__ B,
    const float* __restrict__ bias, const float* __restrict__ resid,
    float* __restrict__ C, ushort* __restrict__ qkvb, int N, int K) {
  __shared__ bf16 sA[2][128 * 32];
  __shared__ bf16 sB[2][128 * 32];
  const int tid  = threadIdx.x;
  const int brow = blockIdx.y * 128;
  const int bcol = blockIdx.x * 128;
  const int wid  = tid >> 6;
  const int lane = tid & 63;
  const int wr   = wid >> 1;
  const int wc   = wid & 1;
  const int fr   = lane & 15;
  const int fk   = lane >> 4;

  fx4 acc[4][4];
#pragma unroll
  for (int i = 0; i < 4; ++i)
#pragma unroll
    for (int j = 0; j < 4; ++j) acc[i][j] = 0.f;

  const int arow = tid >> 2;
  const int acol = (tid & 3) * 8;

  auto stage = [&](int buf, int kt) {
#pragma unroll
    for (int is = 0; is < 2; ++is) {
      const int row = is * 64 + arow;
      const int off = row * 64 + acol * 2;
      g2l16(A + (size_t)(brow + row) * K + kt + acol, (char*)sA[buf] + off);
      g2l16(B + (size_t)(bcol + row) * K + kt + acol, (char*)sB[buf] + off);
    }
  };

  stage(0, 0);
  asm volatile("s_waitcnt vmcnt(0)" ::: "memory");
  __builtin_amdgcn_s_barrier();
  asm volatile("" ::: "memory");

  const int nk = K >> 5;
  int cur = 0;
#pragma unroll 1
  for (int ki = 0; ki < nk; ++ki) {
    if (ki + 1 < nk) stage(cur ^ 1, (ki + 1) * 32);  // prefetch next K-slab
    asm volatile("" ::: "memory");                   // keep reads below issue

    bx8 af[4], bfr[4];
#pragma unroll
    for (int mm = 0; mm < 4; ++mm)
      af[mm] = *(const bx8*)(sA[cur] + (wr * 64 + mm * 16 + fr) * 32 + fk * 8);
#pragma unroll
    for (int nn = 0; nn < 4; ++nn)
      bfr[nn] = *(const bx8*)(sB[cur] + (wc * 64 + nn * 16 + fr) * 32 + fk * 8);
#pragma unroll
    for (int mm = 0; mm < 4; ++mm)
#pragma unroll
      for (int nn = 0; nn < 4; ++nn)
        acc[mm][nn] = __builtin_amdgcn_mfma_f32_16x16x32_bf16(
            af[mm], bfr[nn], acc[mm][nn], 0, 0, 0);

    if (ki + 1 < nk) {  // prefetch had the whole compute phase in flight
      asm volatile("s_waitcnt vmcnt(0)" ::: "memory");
      __builtin_amdgcn_s_barrier();
      asm volatile("" ::: "memory");
    }
    cur ^= 1;
  }

  // C/D layout: col = lane&15, row = (lane>>4)*4 + reg
  const int row0 = brow + wr * 64 + fk * 4;
  const int col0 = bcol + wc * 64 + fr;
#pragma unroll
  for (int mm = 0; mm < 4; ++mm) {
#pragma unroll
    for (int nn = 0; nn < 4; ++nn) {
      const int col = col0 + nn * 16;
      const float bv = bias[col];
      if (EPI == 1) {
#pragma unroll
        for (int rr = 0; rr < 4; ++rr) {
          const int row = row0 + mm * 16 + rr;
          C[(size_t)row * N + col] = acc[mm][nn][rr] + bv + resid[(size_t)row * N + col];
        }
      } else {  // EPI == 2
        const int which = col >> 10;          // 0=q 1=k 2=v
        const int rem   = col & 1023;
        const int hh    = rem >> 6;
        const int dh    = rem & 63;
        // q scaled by DH^-0.5 * log2(e): softmax runs in exp2 domain
        const float scale = (which == 0) ? 0.18033688f : 1.0f;
#pragma unroll
        for (int rr = 0; rr < 4; ++rr) {
          const int row = row0 + mm * 16 + rr;  // t = s*B + b
          const int ss2 = row >> 2, bb2 = row & 3;
          const float v = (acc[mm][nn][rr] + bv) * scale;
          qkvb[(size_t)which * 4194304 +
               ((size_t)(bb2 * 16 + hh)) * 65536 + (size_t)ss2 * 64 + dh] = f2bf(v);
        }
      }
    }
  }
}

// ---------------- V [bh][s][64] -> V^T [bh][dh][1024] ----------------
__global__ __launch_bounds__(256) void transpose_v(
    const ushort* __restrict__ v, ushort* __restrict__ vt) {
  __shared__ ushort tile[64][65];
  const int g  = blockIdx.x;
  const int bh = g >> 4, st = g & 15;
  const int s0 = st * 64;
  const int tid = threadIdx.x;
  const int r  = tid >> 2;          // 0..63
  const int c0 = (tid & 3) * 16;    // 0,16,32,48
  const ushort* src = v + (size_t)bh * 65536 + (size_t)(s0 + r) * 64 + c0;
#pragma unroll
  for (int i = 0; i < 2; ++i) {
    const bx8 d = *(const bx8*)(src + i * 8);
#pragma unroll
    for (int j = 0; j < 8; ++j) tile[r][c0 + i * 8 + j] = (ushort)d[j];
  }
  __syncthreads();
  // write row dh=r, s range [s0+c0, s0+c0+16)
  ushort* dst = vt + (size_t)bh * 65536 + (size_t)r * 1024 + s0 + c0;
  bx8 w0, w1;
#pragma unroll
  for (int j = 0; j < 8; ++j) {
    w0[j] = (short)tile[c0 + j][r];
    w1[j] = (short)tile[c0 + 8 + j][r];
  }
  *(bx8*)dst = w0;
  *(bx8*)(dst + 8) = w1;
}

// ---------------- MFMA flash attention ----------------
// One q-tile (64 rows) per block, grid 1024 = 4 blocks/CU (LDS 160KiB/CU
// exactly). Big tiles dispatched first (qt = 15 - g/64) to kill the tail.
// Swapped S^T = mfma(K,Q); exp2-domain softmax (log2e folded into q);
// truncating bf16 P-pack; 2-phase pipelined LDS, defer-max, setprio.
__global__ __launch_bounds__(256, 4) void attn_mfma(
    const ushort* __restrict__ qb, const ushort* __restrict__ kb,
    const ushort* __restrict__ vtb, ushort* __restrict__ ob) {
  __shared__ __align__(16) char sK[2][8192];
  __shared__ __align__(16) char sVT[2][8192];
  __shared__ __align__(16) char sP[8192];
  const int tid  = threadIdx.x;
  const int wid  = tid >> 6;
  const int lane = tid & 63;
  const int g    = blockIdx.x;
  const int qt   = 15 - (g >> 6);   // descending work
  const int bh   = g & 63;
  const int b    = bh >> 4, h = bh & 15;
  const int fr   = lane & 15;
  const int fk   = lane >> 4;
  const size_t bhoff = (size_t)bh * 65536;
  char* const sPw = sP + wid * 2048;
  const int swp = (fr & 7) << 4;   // P-row swizzle for this lane's q-row

  auto stage = [&](int buf, int k0) {
#pragma unroll
    for (int is = 0; is < 2; ++is) {
      const int L    = is * 4096 + tid * 16;
      const int row  = L >> 7;
      const int colb = (L & 127) ^ ((row & 7) << 4);
      g2l16(kb  + bhoff + (size_t)(k0 + row) * 64 + (colb >> 1), sK[buf]  + L);
      g2l16(vtb + bhoff + (size_t)row * 1024 + k0 + (colb >> 1), sVT[buf] + L);
    }
  };

  const int q0w = qt * 64 + wid * 16;
  const ushort* qp = qb + bhoff + (size_t)(q0w + fr) * 64;
  const bx8 qf0 = *(const bx8*)(qp + fk * 8);
  const bx8 qf1 = *(const bx8*)(qp + 32 + fk * 8);
  asm volatile("s_waitcnt vmcnt(0)" ::: "memory");  // exact vmcnt counting

  fx4 o4[4];
  float m = -3e38f, l = 0.f;
#pragma unroll
  for (int dt = 0; dt < 4; ++dt) o4[dt] = 0.f;

  stage(0, 0);
  int cur = 0;

#pragma unroll 1
  for (int kbk = 0; kbk <= qt; ++kbk) {
    if (kbk < qt) {
      stage(cur ^ 1, (kbk + 1) * 64);                   // prefetch next
      asm volatile("s_waitcnt vmcnt(4)" ::: "memory");  // cur landed
    } else {
      asm volatile("s_waitcnt vmcnt(0)" ::: "memory");
    }
    __builtin_amdgcn_s_barrier();
    asm volatile("" ::: "memory");
    const char* sKc  = sK[cur];
    const char* sVTc = sVT[cur];

    // --- S^T = mfma(K, Q): s4[kt][rr] = S[key=kt*16+fk*4+rr][q=fr] ---
    fx4 s4[4];
    __builtin_amdgcn_s_setprio(1);
#pragma unroll
    for (int kt = 0; kt < 4; ++kt) {
      const int krow = kt * 16 + fr;
      const int sw   = (krow & 7) << 4;
      const bx8 kf0 = *(const bx8*)(sKc + krow * 128 + ((fk * 16) ^ sw));
      const bx8 kf1 = *(const bx8*)(sKc + krow * 128 + ((64 + fk * 16) ^ sw));
      fx4 z = {0.f, 0.f, 0.f, 0.f};
      z = __builtin_amdgcn_mfma_f32_16x16x32_bf16(kf0, qf0, z, 0, 0, 0);
      s4[kt] = __builtin_amdgcn_mfma_f32_16x16x32_bf16(kf1, qf1, z, 0, 0, 0);
    }
    __builtin_amdgcn_s_setprio(0);

    if (kbk == qt) {  // diagonal: mask key-local > q-local (wave-relative)
      const int qloc = wid * 16 + fr;
#pragma unroll
      for (int kt = 0; kt < 4; ++kt) {
        const int keyb = kt * 16 + fk * 4;
#pragma unroll
        for (int rr = 0; rr < 4; ++rr)
          if (keyb + rr > qloc) s4[kt][rr] = -3e38f;
      }
    }

    // --- online softmax in exp2 domain: lane owns q=fr ---
    float pm = s4[0][0];
#pragma unroll
    for (int kt = 0; kt < 4; ++kt)
#pragma unroll
      for (int rr = 0; rr < 4; ++rr) pm = fmaxf(pm, s4[kt][rr]);
    pm = fmaxf(pm, __shfl_xor(pm, 16));
    pm = fmaxf(pm, __shfl_xor(pm, 32));

    if (__any(pm > m + 11.5f)) {   // defer-max (T13), 8 nats = 11.54 bits
      const float mn = fmaxf(m, pm);
      const float f  = exp2f(m - mn);
      m = mn;
      l *= f;
      float fq[4];
#pragma unroll
      for (int rr = 0; rr < 4; ++rr) fq[rr] = __shfl(f, fk * 4 + rr);
#pragma unroll
      for (int dt = 0; dt < 4; ++dt)
#pragma unroll
        for (int rr = 0; rr < 4; ++rr) o4[dt][rr] *= fq[rr];
    }

    // --- P = exp2(S-m), truncating bf16 pack, b64 LDS writes ---
#pragma unroll
    for (int kt = 0; kt < 4; ++kt) {
      union { float f; unsigned u; } a0, a1, a2, a3;
      a0.f = exp2f(s4[kt][0] - m);
      a1.f = exp2f(s4[kt][1] - m);
      a2.f = exp2f(s4[kt][2] - m);
      a3.f = exp2f(s4[kt][3] - m);
      l += (a0.f + a1.f) + (a2.f + a3.f);
      uint2 pk;
      pk.x = (a0.u >> 16) | (a1.u & 0xFFFF0000u);
      pk.y = (a2.u >> 16) | (a3.u & 0xFFFF0000u);
      *(uint2*)(sPw + ((fr * 128 + kt * 32 + fk * 8) ^ swp)) = pk;
    }

    // --- O += P V ---
    __builtin_amdgcn_s_setprio(1);
#pragma unroll
    for (int c = 0; c < 2; ++c) {
      const bx8 pa = *(const bx8*)(sPw + ((fr * 128 + c * 64 + fk * 16) ^ swp));
#pragma unroll
      for (int dt = 0; dt < 4; ++dt) {
        const int vrow = dt * 16 + fr;
        const bx8 vf = *(const bx8*)(sVTc + vrow * 128 +
                                     ((c * 64 + fk * 16) ^ ((vrow & 7) << 4)));
        o4[dt] = __builtin_amdgcn_mfma_f32_16x16x32_bf16(pa, vf, o4[dt], 0, 0, 0);
      }
    }
    __builtin_amdgcn_s_setprio(0);

    asm volatile("" ::: "memory");
    __builtin_amdgcn_s_barrier();   // readers done before next overwrite
    asm volatile("" ::: "memory");
    cur ^= 1;
  }

  // --- epilogue: total row sums, fetch per-output-row norms, store ---
  l += __shfl_xor(l, 16);
  l += __shfl_xor(l, 32);
  const float linv = 1.f / l;
  float lq[4];
#pragma unroll
  for (int rr = 0; rr < 4; ++rr) lq[rr] = __shfl(linv, fk * 4 + rr);

#pragma unroll
  for (int dt = 0; dt < 4; ++dt) {
#pragma unroll
    for (int rr = 0; rr < 4; ++rr) {
      const int qq = q0w + fk * 4 + rr;
      ob[((size_t)qq * 4 + b) * 1024 + h * 64 + dt * 16 + fr] =
          f2bf(o4[dt][rr] * lq[rr]);
    }
  }
}

// ---------------- LN2 + router + gate + final multiply ----------------
__global__ __launch_bounds__(256) void final_kernel(
    const float* __restrict__ xn, const float* __restrict__ w,
    const float* __restrict__ bb, const float* __restrict__ gw,
    float* __restrict__ out, float* __restrict__ rlog) {
  const int t = blockIdx.x, tid = threadIdx.x;
  const fx4 v = ((const fx4*)(xn + (size_t)t * D_DIM))[tid];
  float s  = v[0] + v[1] + v[2] + v[3];
  float ss = v[0]*v[0] + v[1]*v[1] + v[2]*v[2] + v[3]*v[3];
#pragma unroll
  for (int off = 32; off >= 1; off >>= 1) {
    s  += __shfl_xor(s, off);
    ss += __shfl_xor(ss, off);
  }
  __shared__ float red[8];
  __shared__ float red2[12];
  const int wid = tid >> 6, lane = tid & 63;
  if (lane == 0) { red[wid] = s; red[4 + wid] = ss; }
  __syncthreads();
  s  = red[0] + red[1] + red[2] + red[3];
  ss = red[4] + red[5] + red[6] + red[7];
  const float mu = s * (1.f / D_DIM);
  const float rstd = rsqrtf(ss * (1.f / D_DIM) - mu * mu + 1e-5f);
  const fx4 wv = ((const fx4*)w)[tid];
  const fx4 bv = ((const fx4*)bb)[tid];
  fx4 hv;
#pragma unroll
  for (int cc = 0; cc < 4; ++cc) hv[cc] = (v[cc] - mu) * rstd * wv[cc] + bv[cc];

  const fx4 w0 = ((const fx4*)(gw           ))[tid];
  const fx4 w1 = ((const fx4*)(gw +     D_DIM))[tid];
  const fx4 w2 = ((const fx4*)(gw + 2 * D_DIM))[tid];
  float g0 = hv[0]*w0[0] + hv[1]*w0[1] + hv[2]*w0[2] + hv[3]*w0[3];
  float g1 = hv[0]*w1[0] + hv[1]*w1[1] + hv[2]*w1[2] + hv[3]*w1[3];
  float g2 = hv[0]*w2[0] + hv[1]*w2[1] + hv[2]*w2[2] + hv[3]*w2[3];
#pragma unroll
  for (int off = 32; off >= 1; off >>= 1) {
    g0 += __shfl_xor(g0, off);
    g1 += __shfl_xor(g1, off);
    g2 += __shfl_xor(g2, off);
  }
  if (lane == 0) { red2[wid] = g0; red2[4 + wid] = g1; red2[8 + wid] = g2; }
  __syncthreads();
  g0 = red2[0] + red2[1] + red2[2]  + red2[3];
  g1 = red2[4] + red2[5] + red2[6]  + red2[7];
  g2 = red2[8] + red2[9] + red2[10] + red2[11];

  // gate = pmax/(pmax+p2nd) of softmax over 3 = 1/(1+exp(l_mid - l_max))
  const float lmax = fmaxf(g0, fmaxf(g1, g2));
  const float lmin = fminf(g0, fminf(g1, g2));
  const float lmid = (g0 + g1 + g2) - lmax - lmin;
  const float gate = 1.f / (1.f + __expf(lmid - lmax));

  ((fx4*)(out + (size_t)t * D_DIM))[tid] = v * gate;
  if (tid == 0) {
    rlog[(size_t)t * 3 + 0] = g0;
    rlog[(size_t)t * 3 + 1] = g1;
    rlog[(size_t)t * 3 + 2] = g2;
  }
}

extern "C" void kernel_launch(void* const* d_in, const int* in_sizes, int n_in,
                              void* d_out, int out_size, void* d_ws, size_t ws_size,
                              hipStream_t stream) {
  (void)in_sizes; (void)n_in; (void)out_size; (void)ws_size;
  const float* x    = (const float*)d_in[0];
  const float* ln1w = (const float*)d_in[1];
  const float* ln1b = (const float*)d_in[2];
  const float* ln2w = (const float*)d_in[3];
  const float* ln2b = (const float*)d_in[4];
  const float* win  = (const float*)d_in[5];
  const float* bin  = (const float*)d_in[6];
  const float* wout = (const float*)d_in[7];
  const float* bout = (const float*)d_in[8];
  const float* gw   = (const float*)d_in[9];
  // fc_w / fc_b / proj_w / proj_b (d_in[10..13]) are dead code in the reference.

  char* ws = (char*)d_ws;
  bf16*   w_in_b  = (bf16*)(ws);               // 6 MiB
  bf16*   w_out_b = (bf16*)(ws + 6291456);     // 2 MiB
  bf16*   h_b     = (bf16*)(ws + 8388608);     // 8 MiB (LN1 out; o_b aliases)
  ushort* o_b     = (ushort*)h_b;              // alias: h dead after GEMM1
  ushort* qkvb    = (ushort*)(ws + 16777216);  // 24 MiB: q/k/v bf16 [bh][s][64]
  ushort* q_b     = qkvb;
  ushort* k_b     = qkvb + 4194304;
  ushort* v_b     = qkvb + 8388608;
  float*  xnew    = (float*)(ws + 41943040);   // 16 MiB
  ushort* vt_b    = (ushort*)(ws + 58720256);  // 8 MiB: V^T [bh][dh][s]
  // total ws use: 64 MiB

  float* out  = (float*)d_out;
  float* rlog = out + (size_t)T_DIM * D_DIM;

  cast2_f32_bf16<<<4096, 256, 0, stream>>>(win, w_in_b, 786432,
                                           wout, w_out_b, 262144);
  ln_bf16_kernel<<<T_DIM, 256, 0, stream>>>(x, ln1w, ln1b, h_b);
  gemm_bt<2><<<dim3(QKV_N / 128, T_DIM / 128), 256, 0, stream>>>(
      h_b, w_in_b, bin, nullptr, nullptr, qkvb, QKV_N, D_DIM);
  transpose_v<<<1024, 256, 0, stream>>>(v_b, vt_b);
  attn_mfma<<<1024, 256, 0, stream>>>(q_b, k_b, vt_b, o_b);
  gemm_bt<1><<<dim3(D_DIM / 128, T_DIM / 128), 256, 0, stream>>>(
      (const bf16*)o_b, w_out_b, bout, x, xnew, nullptr, D_DIM, D_DIM);
  final_kernel<<<T_DIM, 256, 0, stream>>>(xnew, ln2w, ln2b, gw, out, rlog);
}